// Round 5
// baseline (298.253 us; speedup 1.0000x reference)
//
#include <hip/hip_runtime.h>
#include <hip/hip_bf16.h>
#include <hip/hip_fp16.h>

// Problem constants: B=1,R=2,D=256,NH=8,NP=8,ZA=4,H=W=128,Q=16384,HD=32
#define QN 16384
#define DK 256

typedef float f4_t __attribute__((ext_vector_type(4)));
typedef short s16x8 __attribute__((ext_vector_type(8)));
typedef short s16x4 __attribute__((ext_vector_type(4)));
typedef unsigned int u32;
typedef u32 u32x4 __attribute__((ext_vector_type(4)));
typedef __fp16 h2_t __attribute__((ext_vector_type(2)));

__device__ inline short f2bf(float f){
  __hip_bfloat16 h = __float2bfloat16(f);
  return __builtin_bit_cast(short, h);
}
__device__ inline short f2h16(float f){
  __half h = __float2half(f);
  return __builtin_bit_cast(short, h);
}
__device__ inline float dot2h(u32 a, u32 b, float c){
#if __has_builtin(__builtin_amdgcn_fdot2)
  return __builtin_amdgcn_fdot2(__builtin_bit_cast(h2_t, a),
                                __builtin_bit_cast(h2_t, b), c, false);
#else
  h2_t ha = __builtin_bit_cast(h2_t, a), hb = __builtin_bit_cast(h2_t, b);
  return c + (float)ha[0] * (float)hb[0] + (float)ha[1] * (float)hb[1];
#endif
}
__device__ inline u32 pk2h(float a, float b){
#if __has_builtin(__builtin_amdgcn_cvt_pkrtz)
  h2_t r = __builtin_amdgcn_cvt_pkrtz(a, b);
  return __builtin_bit_cast(u32, r);
#else
  return (u32)__builtin_bit_cast(unsigned short, __float2half(a)) |
         ((u32)__builtin_bit_cast(unsigned short, __float2half(b)) << 16);
#endif
}
__device__ inline u32 bperm(u32 s0, u32 s1, u32 sel){
  // D.byte[i] = sel.byte[i] from {S0:S1}: indices 0-3 pick S1 bytes, 4-7 pick S0.
  return __builtin_amdgcn_perm(s0, s1, sel);
}

// ---------------- weight pre-convert (f32 -> bf16, row-major K=256) -------------
// rows 0..255 = W_val, 256..383 = W_off, 384..447 = W_attn, 448..703 = W_out
__global__ __launch_bounds__(256) void k_convw(const float* __restrict__ Wv,
    const float* __restrict__ Woff, const float* __restrict__ Wattn,
    const float* __restrict__ Wout, short* __restrict__ Wbf){
  const int row = blockIdx.x;
  const int c = threadIdx.x;
  const float* src;
  if (row < 256)       src = Wv    + (size_t)row * DK;
  else if (row < 384)  src = Woff  + (size_t)(row - 256) * DK;
  else if (row < 448)  src = Wattn + (size_t)(row - 384) * DK;
  else                 src = Wout  + (size_t)(row - 448) * DK;
  Wbf[(size_t)row * DK + c] = f2bf(src[c]);
}

// =============== K1: value projection, LDS-staged MFMA GEMM =====================
// Output stored as FP16 (for the sampler's v_dot2_f32_f16 inner loop).
__global__ __launch_bounds__(256, 2) void k_gemm_val(const float* __restrict__ A,
    const short* __restrict__ Bw, const float* __restrict__ bval,
    short* __restrict__ vhf){
  __shared__ short As[64 * 256];
  __shared__ short Bs[64 * 256];
  const int tid = threadIdx.x;
  const int lane = tid & 63, wv = tid >> 6;
  const int r16 = lane & 15, kh = lane >> 4;
  const int swsel = (r16 & 7) << 4;
  const int mbase = blockIdx.x * 64;

  #pragma unroll
  for (int i = 0; i < 16; ++i){
    const int lin = i * 256 + tid;
    const int r = lin >> 6, ck = lin & 63;
    const f4_t v = *(const f4_t*)(A + (size_t)(mbase + r) * DK + ck * 4);
    s16x4 o = { f2bf(v[0]), f2bf(v[1]), f2bf(v[2]), f2bf(v[3]) };
    *(s16x4*)((char*)As + r * 512 + ((ck * 8) ^ ((r & 7) << 4))) = o;
  }
  s16x8 breg[8];
  #pragma unroll
  for (int i = 0; i < 8; ++i){
    const int lin = i * 256 + tid;
    const int n = lin >> 5, ck = lin & 31;
    breg[i] = *(const s16x8*)(Bw + (size_t)n * DK + ck * 8);
  }
  __syncthreads();

  for (int cg = 0; cg < 4; ++cg){
    #pragma unroll
    for (int i = 0; i < 8; ++i){
      const int lin = i * 256 + tid;
      const int n = lin >> 5, ck = lin & 31;
      *(s16x8*)((char*)Bs + n * 512 + ((ck * 16) ^ ((n & 7) << 4))) = breg[i];
    }
    __syncthreads();
    if (cg < 3){
      #pragma unroll
      for (int i = 0; i < 8; ++i){
        const int lin = i * 256 + tid;
        const int n = lin >> 5, ck = lin & 31;
        breg[i] = *(const s16x8*)(Bw + (size_t)((cg + 1) * 64 + n) * DK + ck * 8);
      }
    }
    f4_t acc[4];
    #pragma unroll
    for (int i = 0; i < 4; ++i) acc[i] = (f4_t){0.f, 0.f, 0.f, 0.f};
    #pragma unroll
    for (int kk = 0; kk < 8; ++kk){
      const int kb = kh * 16 + kk * 64;
      const s16x8 a = *(const s16x8*)((char*)As + (wv * 16 + r16) * 512 + (kb ^ swsel));
      #pragma unroll
      for (int nt = 0; nt < 4; ++nt){
        const s16x8 b = *(const s16x8*)((char*)Bs + (nt * 16 + r16) * 512 + (kb ^ swsel));
        acc[nt] = __builtin_amdgcn_mfma_f32_16x16x32_bf16(a, b, acc[nt], 0, 0, 0);
      }
    }
    #pragma unroll
    for (int nt = 0; nt < 4; ++nt){
      const int n = cg * 64 + nt * 16 + r16;
      const int h = n >> 5, hd = n & 31;
      const float bv = bval[n];
      #pragma unroll
      for (int rix = 0; rix < 4; ++rix){
        const int m = mbase + wv * 16 + kh * 4 + rix;
        const int r = m >> 14, pix = m & (QN - 1);
        vhf[(size_t)((r * 8 + h) * QN + pix) * 32 + hd] = f2h16(acc[nt][rix] + bv);
      }
    }
    __syncthreads();
  }
}

// =============== K2: offsets + logits, BM=32 variant ============================
__global__ __launch_bounds__(256, 2) void k_gemm_oa(const float* __restrict__ A,
    const short* __restrict__ Bw, const float* __restrict__ boff,
    const float* __restrict__ battn, float* __restrict__ offw,
    float* __restrict__ logit){
  __shared__ short As[32 * 256];
  __shared__ short Bs[64 * 256];
  const int tid = threadIdx.x;
  const int lane = tid & 63, wv = tid >> 6;
  const int r16 = lane & 15, kh = lane >> 4;
  const int mg = wv & 1, ch = wv >> 1;
  const int swsel = (r16 & 7) << 4;
  const int mbase = blockIdx.x * 32;

  #pragma unroll
  for (int i = 0; i < 8; ++i){
    const int lin = i * 256 + tid;
    const int r = lin >> 6, ck = lin & 63;
    const f4_t v = *(const f4_t*)(A + (size_t)(mbase + r) * DK + ck * 4);
    s16x4 o = { f2bf(v[0]), f2bf(v[1]), f2bf(v[2]), f2bf(v[3]) };
    *(s16x4*)((char*)As + r * 512 + ((ck * 8) ^ ((r & 7) << 4))) = o;
  }
  s16x8 breg[8];
  #pragma unroll
  for (int i = 0; i < 8; ++i){
    const int lin = i * 256 + tid;
    const int n = lin >> 5, ck = lin & 31;
    breg[i] = *(const s16x8*)(Bw + (size_t)n * DK + ck * 8);
  }
  __syncthreads();

  for (int cg = 0; cg < 3; ++cg){
    #pragma unroll
    for (int i = 0; i < 8; ++i){
      const int lin = i * 256 + tid;
      const int n = lin >> 5, ck = lin & 31;
      *(s16x8*)((char*)Bs + n * 512 + ((ck * 16) ^ ((n & 7) << 4))) = breg[i];
    }
    __syncthreads();
    if (cg < 2){
      #pragma unroll
      for (int i = 0; i < 8; ++i){
        const int lin = i * 256 + tid;
        const int n = lin >> 5, ck = lin & 31;
        breg[i] = *(const s16x8*)(Bw + (size_t)((cg + 1) * 64 + n) * DK + ck * 8);
      }
    }
    f4_t acc[2];
    acc[0] = (f4_t){0.f,0.f,0.f,0.f}; acc[1] = (f4_t){0.f,0.f,0.f,0.f};
    #pragma unroll
    for (int kk = 0; kk < 8; ++kk){
      const int kb = kh * 16 + kk * 64;
      const s16x8 a = *(const s16x8*)((char*)As + (mg * 16 + r16) * 512 + (kb ^ swsel));
      #pragma unroll
      for (int nt = 0; nt < 2; ++nt){
        const s16x8 b = *(const s16x8*)((char*)Bs + (ch * 32 + nt * 16 + r16) * 512 + (kb ^ swsel));
        acc[nt] = __builtin_amdgcn_mfma_f32_16x16x32_bf16(a, b, acc[nt], 0, 0, 0);
      }
    }
    #pragma unroll
    for (int nt = 0; nt < 2; ++nt){
      const int n = cg * 64 + ch * 32 + nt * 16 + r16;
      #pragma unroll
      for (int rix = 0; rix < 4; ++rix){
        const int m = mbase + mg * 16 + kh * 4 + rix;
        const float v = acc[nt][rix];
        if (n < 128) offw[(size_t)m * 128 + n] = v + boff[n];
        else         logit[(size_t)m * 64 + (n - 128)] = v + battn[n - 128];
      }
    }
    __syncthreads();
  }
}

// =============== K4: output projection + bias + residual, BM=32 =================
__global__ __launch_bounds__(256, 2) void k_gemm_out(const float* __restrict__ A,
    const short* __restrict__ Bw, const float* __restrict__ bout,
    const float* __restrict__ query, float* __restrict__ out){
  __shared__ short As[32 * 256];
  __shared__ short Bs[64 * 256];
  const int tid = threadIdx.x;
  const int lane = tid & 63, wv = tid >> 6;
  const int r16 = lane & 15, kh = lane >> 4;
  const int mg = wv & 1, ch = wv >> 1;
  const int swsel = (r16 & 7) << 4;
  const int mbase = blockIdx.x * 32;

  #pragma unroll
  for (int i = 0; i < 8; ++i){
    const int lin = i * 256 + tid;
    const int r = lin >> 6, ck = lin & 63;
    const f4_t v = *(const f4_t*)(A + (size_t)(mbase + r) * DK + ck * 4);
    s16x4 o = { f2bf(v[0]), f2bf(v[1]), f2bf(v[2]), f2bf(v[3]) };
    *(s16x4*)((char*)As + r * 512 + ((ck * 8) ^ ((r & 7) << 4))) = o;
  }
  s16x8 breg[8];
  #pragma unroll
  for (int i = 0; i < 8; ++i){
    const int lin = i * 256 + tid;
    const int n = lin >> 5, ck = lin & 31;
    breg[i] = *(const s16x8*)(Bw + (size_t)n * DK + ck * 8);
  }
  __syncthreads();

  for (int cg = 0; cg < 4; ++cg){
    #pragma unroll
    for (int i = 0; i < 8; ++i){
      const int lin = i * 256 + tid;
      const int n = lin >> 5, ck = lin & 31;
      *(s16x8*)((char*)Bs + n * 512 + ((ck * 16) ^ ((n & 7) << 4))) = breg[i];
    }
    __syncthreads();
    if (cg < 3){
      #pragma unroll
      for (int i = 0; i < 8; ++i){
        const int lin = i * 256 + tid;
        const int n = lin >> 5, ck = lin & 31;
        breg[i] = *(const s16x8*)(Bw + (size_t)((cg + 1) * 64 + n) * DK + ck * 8);
      }
    }
    f4_t acc[2];
    acc[0] = (f4_t){0.f,0.f,0.f,0.f}; acc[1] = (f4_t){0.f,0.f,0.f,0.f};
    #pragma unroll
    for (int kk = 0; kk < 8; ++kk){
      const int kb = kh * 16 + kk * 64;
      const s16x8 a = *(const s16x8*)((char*)As + (mg * 16 + r16) * 512 + (kb ^ swsel));
      #pragma unroll
      for (int nt = 0; nt < 2; ++nt){
        const s16x8 b = *(const s16x8*)((char*)Bs + (ch * 32 + nt * 16 + r16) * 512 + (kb ^ swsel));
        acc[nt] = __builtin_amdgcn_mfma_f32_16x16x32_bf16(a, b, acc[nt], 0, 0, 0);
      }
    }
    #pragma unroll
    for (int nt = 0; nt < 2; ++nt){
      const int n = cg * 64 + ch * 32 + nt * 16 + r16;
      const float bo = bout[n];
      #pragma unroll
      for (int rix = 0; rix < 4; ++rix){
        const int m = mbase + mg * 16 + kh * 4 + rix;
        out[(size_t)m * DK + n] = acc[nt][rix] + bo + query[(size_t)m * DK + n];
      }
    }
    __syncthreads();
  }
}

// ---------------- K3: bilinear deformable sampling (restructured) ----------------
// 4-lane group per query; lane j computes weights for samples s == j (mod 4) only,
// broadcasts 3 packed words/sample via __shfl; inner loop = v_perm + v_dot2_f32_f16;
// 1-deep explicit load pipeline over the 16 (r,p) samples.
__device__ inline void mkw(float rx, float ry, float ox, float oy, float awp,
                           u32& word, u32& pk01, u32& pk23){
  const float x = fmaf(rx, 128.f, ox) - 0.5f;
  const float y = fmaf(ry, 128.f, oy) - 0.5f;
  const float xf = floorf(x), yf = floorf(y);
  const float wx = x - xf, wy = y - yf;
  const int ix = (int)xf, iy = (int)yf;
  float xw0 = 1.f - wx, xw1 = wx, yw0 = 1.f - wy, yw1 = wy;
  if (ix < 0 || ix > 127)   xw0 = 0.f;
  if (ix < -1 || ix > 126)  xw1 = 0.f;
  if (iy < 0 || iy > 127)   yw0 = 0.f;
  if (iy < -1 || iy > 126)  yw1 = 0.f;
  const int ix0 = min(max(ix, 0), 127), ix1 = min(max(ix + 1, 0), 127);
  const int iy0 = min(max(iy, 0), 127), iy1 = min(max(iy + 1, 0), 127);
  const float t0 = awp * yw0, t1 = awp * yw1;
  pk01 = pk2h(t0 * xw0, t0 * xw1);
  pk23 = pk2h(t1 * xw0, t1 * xw1);
  word = (u32)(iy0 * 128 + ix0) | ((u32)(ix1 - ix0) << 16) | ((u32)(iy1 - iy0) << 17);
}

__global__ __launch_bounds__(256, 4) void k_sampler(const float* __restrict__ rp,
    const float* __restrict__ offw, const float* __restrict__ logit,
    const short* __restrict__ vhf, float* __restrict__ O2){
  const int tid = threadIdx.x;
  const int j = tid & 3;
  const int grp = tid >> 2;
  const int lane = tid & 63;
  const int glane = lane & ~3;
  const int h = blockIdx.x & 7;
  const int q = (blockIdx.x >> 3) * 64 + grp;
  const u32 jof = (u32)j * 8;                 // fp16-element offset of this lane's slice

  // softmax over 8 logits (fold 0.5 mean-over-R); only aw[j], aw[j+4] kept
  const float* lp = logit + (size_t)q * 64 + h * 8;
  const float l0 = lp[0], l1 = lp[1], l2 = lp[2], l3 = lp[3];
  const float l4 = lp[4], l5 = lp[5], l6 = lp[6], l7 = lp[7];
  float mx = fmaxf(fmaxf(fmaxf(l0, l1), fmaxf(l2, l3)),
                   fmaxf(fmaxf(l4, l5), fmaxf(l6, l7)));
  float sum = __expf(l0 - mx) + __expf(l1 - mx) + __expf(l2 - mx) + __expf(l3 - mx)
            + __expf(l4 - mx) + __expf(l5 - mx) + __expf(l6 - mx) + __expf(l7 - mx);
  const float sc = 0.5f / sum;
  const float la = lp[j], lb = lp[j + 4];
  const float wA = __expf(la - mx) * sc;
  const float wB = __expf(lb - mx) * sc;

  // own offsets/refpoints: p = j and p = j+4 (za == j for both), r = 0 and 1
  const float* offp = offw + (size_t)q * 128 + h * 16;
  const float ox0 = offp[2 * j],     oy0 = offp[2 * j + 1];
  const float ox1 = offp[2 * j + 8], oy1 = offp[2 * j + 9];
  const float* rp0 = rp + (size_t)q * 8 + j * 2;
  const float* rp1 = rp + (size_t)(QN + q) * 8 + j * 2;
  const float rx0 = rp0[0], ry0 = rp0[1];
  const float rx1 = rp1[0], ry1 = rp1[1];

  // weights for my 4 samples: k -> s = 4k+j -> (r,p) = (s>>3, s&7)
  u32 wrds[4], pks01[4], pks23[4];
  mkw(rx0, ry0, ox0, oy0, wA, wrds[0], pks01[0], pks23[0]);   // (0, j)
  mkw(rx0, ry0, ox1, oy1, wB, wrds[1], pks01[1], pks23[1]);   // (0, j+4)
  mkw(rx1, ry1, ox0, oy0, wA, wrds[2], pks01[2], pks23[2]);   // (1, j)
  mkw(rx1, ry1, ox1, oy1, wB, wrds[3], pks01[3], pks23[3]);   // (1, j+4)

  const short* vb0 = vhf + (size_t)(h * QN) * 32;
  const short* vb1 = vhf + (size_t)((8 + h) * QN) * 32;

  float acc[8] = {0.f,0.f,0.f,0.f,0.f,0.f,0.f,0.f};
  u32x4 cb00[2], cb01[2], cb10[2], cb11[2];
  u32 wbuf01[2], wbuf23[2];

#define FETCH(S, P) do{                                                     \
    const int srcl_ = glane | ((S) & 3);                                    \
    wbuf01[P] = __shfl(pks01[(S) >> 2], srcl_);                             \
    wbuf23[P] = __shfl(pks23[(S) >> 2], srcl_);                             \
    const u32 wd_ = __shfl(wrds[(S) >> 2], srcl_);                          \
    const u32 o00_ = (wd_ & 0xFFFFu) * 32u + jof;                           \
    const u32 o01_ = o00_ + ((wd_ >> 11) & 32u);                            \
    const u32 dy_ = (wd_ >> 17) & 1u;                                       \
    const u32 o10_ = o00_ + dy_ * 4096u;                                    \
    const u32 o11_ = o01_ + dy_ * 4096u;                                    \
    const short* vb_ = ((S) >> 3) ? vb1 : vb0;                              \
    cb00[P] = *(const u32x4*)(vb_ + o00_);                                  \
    cb01[P] = *(const u32x4*)(vb_ + o01_);                                  \
    cb10[P] = *(const u32x4*)(vb_ + o10_);                                  \
    cb11[P] = *(const u32x4*)(vb_ + o11_);                                  \
  }while(0)

  FETCH(0, 0);
  #pragma unroll
  for (int s = 0; s < 16; ++s){
    if (s < 15) FETCH(s + 1, (s + 1) & 1);
    const int P = s & 1;
    #pragma unroll
    for (int e = 0; e < 4; ++e){
      const u32 p0 = bperm(cb01[P][e], cb00[P][e], 0x05040100u);
      const u32 p1 = bperm(cb01[P][e], cb00[P][e], 0x07060302u);
      const u32 q0 = bperm(cb11[P][e], cb10[P][e], 0x05040100u);
      const u32 q1 = bperm(cb11[P][e], cb10[P][e], 0x07060302u);
      acc[2*e]   = dot2h(p0, wbuf01[P], acc[2*e]);
      acc[2*e+1] = dot2h(p1, wbuf01[P], acc[2*e+1]);
      acc[2*e]   = dot2h(q0, wbuf23[P], acc[2*e]);
      acc[2*e+1] = dot2h(q1, wbuf23[P], acc[2*e+1]);
    }
  }
#undef FETCH

  float* op = O2 + (size_t)q * DK + h * 32 + j * 8;
  *(f4_t*)op       = (f4_t){acc[0], acc[1], acc[2], acc[3]};
  *(f4_t*)(op + 4) = (f4_t){acc[4], acc[5], acc[6], acc[7]};
}

extern "C" void kernel_launch(void* const* d_in, const int* in_sizes, int n_in,
                              void* d_out, int out_size, void* d_ws, size_t ws_size,
                              hipStream_t stream) {
  const float* query = (const float*)d_in[0];
  const float* value = (const float*)d_in[1];
  const float* refpt = (const float*)d_in[2];
  // d_in[3] spatial_shapes: fixed [[128,128]], hardcoded
  const float* W_off  = (const float*)d_in[4];
  const float* b_off  = (const float*)d_in[5];
  const float* W_attn = (const float*)d_in[6];
  const float* b_attn = (const float*)d_in[7];
  const float* W_val  = (const float*)d_in[8];
  const float* b_val  = (const float*)d_in[9];
  const float* W_out  = (const float*)d_in[10];
  const float* b_out  = (const float*)d_in[11];
  float* out = (float*)d_out;

  char* ws = (char*)d_ws;
  short* Wbf  = (short*)(ws);                    // 704*256 bf16          (360448 B)
  short* vhf  = (short*)(ws + 360448);           // 2*8*16384*32 fp16     (16777216 B)
  float* offw = (float*)(ws + 17137664);         // 16384*128 f32         (8388608 B)
  float* logit= (float*)(ws + 25526272);         // 16384*64 f32          (4194304 B)
  float* O2   = (float*)(ws + 29720576);         // 16384*256 f32         (16777216 B)

  k_convw   <<<dim3(704),  dim3(256), 0, stream>>>(W_val, W_off, W_attn, W_out, Wbf);
  k_gemm_val<<<dim3(512),  dim3(256), 0, stream>>>(value, Wbf, b_val, vhf);
  k_gemm_oa <<<dim3(512),  dim3(256), 0, stream>>>(query, Wbf + 256 * DK, b_off, b_attn, offw, logit);
  k_sampler <<<dim3(2048), dim3(256), 0, stream>>>(refpt, offw, logit, vhf, O2);
  k_gemm_out<<<dim3(512),  dim3(256), 0, stream>>>(O2, Wbf + 448 * DK, b_out, query, out);
}

// Round 6
// 79.374 us; speedup vs baseline: 3.7576x; 3.7576x over previous
//
#include <hip/hip_runtime.h>
#include <hip/hip_bf16.h>
#include <hip/hip_fp16.h>

// Problem constants: B=1,R=2,D=256,NH=8,NP=8,ZA=4,H=W=128,Q=16384,HD=32
#define QN 16384
#define DK 256

typedef float f4_t __attribute__((ext_vector_type(4)));
typedef short s16x8 __attribute__((ext_vector_type(8)));
typedef short s16x4 __attribute__((ext_vector_type(4)));
typedef unsigned int u32;
typedef u32 u32x4 __attribute__((ext_vector_type(4)));
typedef __fp16 h2_t __attribute__((ext_vector_type(2)));

__device__ inline short f2bf(float f){
  __hip_bfloat16 h = __float2bfloat16(f);
  return __builtin_bit_cast(short, h);
}
__device__ inline short f2h16(float f){
  __half h = __float2half(f);
  return __builtin_bit_cast(short, h);
}
__device__ inline float dot2h(u32 a, u32 b, float c){
#if __has_builtin(__builtin_amdgcn_fdot2)
  return __builtin_amdgcn_fdot2(__builtin_bit_cast(h2_t, a),
                                __builtin_bit_cast(h2_t, b), c, false);
#else
  h2_t ha = __builtin_bit_cast(h2_t, a), hb = __builtin_bit_cast(h2_t, b);
  return c + (float)ha[0] * (float)hb[0] + (float)ha[1] * (float)hb[1];
#endif
}
__device__ inline u32 pk2h(float a, float b){
#if __has_builtin(__builtin_amdgcn_cvt_pkrtz)
  h2_t r = __builtin_amdgcn_cvt_pkrtz(a, b);
  return __builtin_bit_cast(u32, r);
#else
  return (u32)__builtin_bit_cast(unsigned short, __float2half(a)) |
         ((u32)__builtin_bit_cast(unsigned short, __float2half(b)) << 16);
#endif
}
__device__ inline u32 bperm(u32 s0, u32 s1, u32 sel){
  return __builtin_amdgcn_perm(s0, s1, sel);
}

// ---------------- weight pre-convert (f32 -> bf16, row-major K=256) -------------
// rows 0..255 = W_val, 256..383 = W_off, 384..447 = W_attn, 448..703 = W_out
__global__ __launch_bounds__(256) void k_convw(const float* __restrict__ Wv,
    const float* __restrict__ Woff, const float* __restrict__ Wattn,
    const float* __restrict__ Wout, short* __restrict__ Wbf){
  const int row = blockIdx.x;
  const int c = threadIdx.x;
  const float* src;
  if (row < 256)       src = Wv    + (size_t)row * DK;
  else if (row < 384)  src = Woff  + (size_t)(row - 256) * DK;
  else if (row < 448)  src = Wattn + (size_t)(row - 384) * DK;
  else                 src = Wout  + (size_t)(row - 448) * DK;
  Wbf[(size_t)row * DK + c] = f2bf(src[c]);
}

// =============== K1: value projection, LDS-staged MFMA GEMM =====================
// Output stored as FP16 (for the sampler's v_dot2_f32_f16 inner loop).
__global__ __launch_bounds__(256, 2) void k_gemm_val(const float* __restrict__ A,
    const short* __restrict__ Bw, const float* __restrict__ bval,
    short* __restrict__ vhf){
  __shared__ short As[64 * 256];
  __shared__ short Bs[64 * 256];
  const int tid = threadIdx.x;
  const int lane = tid & 63, wv = tid >> 6;
  const int r16 = lane & 15, kh = lane >> 4;
  const int swsel = (r16 & 7) << 4;
  const int mbase = blockIdx.x * 64;

  #pragma unroll
  for (int i = 0; i < 16; ++i){
    const int lin = i * 256 + tid;
    const int r = lin >> 6, ck = lin & 63;
    const f4_t v = *(const f4_t*)(A + (size_t)(mbase + r) * DK + ck * 4);
    s16x4 o = { f2bf(v[0]), f2bf(v[1]), f2bf(v[2]), f2bf(v[3]) };
    *(s16x4*)((char*)As + r * 512 + ((ck * 8) ^ ((r & 7) << 4))) = o;
  }
  s16x8 breg[8];
  #pragma unroll
  for (int i = 0; i < 8; ++i){
    const int lin = i * 256 + tid;
    const int n = lin >> 5, ck = lin & 31;
    breg[i] = *(const s16x8*)(Bw + (size_t)n * DK + ck * 8);
  }
  __syncthreads();

  for (int cg = 0; cg < 4; ++cg){
    #pragma unroll
    for (int i = 0; i < 8; ++i){
      const int lin = i * 256 + tid;
      const int n = lin >> 5, ck = lin & 31;
      *(s16x8*)((char*)Bs + n * 512 + ((ck * 16) ^ ((n & 7) << 4))) = breg[i];
    }
    __syncthreads();
    if (cg < 3){
      #pragma unroll
      for (int i = 0; i < 8; ++i){
        const int lin = i * 256 + tid;
        const int n = lin >> 5, ck = lin & 31;
        breg[i] = *(const s16x8*)(Bw + (size_t)((cg + 1) * 64 + n) * DK + ck * 8);
      }
    }
    f4_t acc[4];
    #pragma unroll
    for (int i = 0; i < 4; ++i) acc[i] = (f4_t){0.f, 0.f, 0.f, 0.f};
    #pragma unroll
    for (int kk = 0; kk < 8; ++kk){
      const int kb = kh * 16 + kk * 64;
      const s16x8 a = *(const s16x8*)((char*)As + (wv * 16 + r16) * 512 + (kb ^ swsel));
      #pragma unroll
      for (int nt = 0; nt < 4; ++nt){
        const s16x8 b = *(const s16x8*)((char*)Bs + (nt * 16 + r16) * 512 + (kb ^ swsel));
        acc[nt] = __builtin_amdgcn_mfma_f32_16x16x32_bf16(a, b, acc[nt], 0, 0, 0);
      }
    }
    #pragma unroll
    for (int nt = 0; nt < 4; ++nt){
      const int n = cg * 64 + nt * 16 + r16;
      const int h = n >> 5, hd = n & 31;
      const float bv = bval[n];
      #pragma unroll
      for (int rix = 0; rix < 4; ++rix){
        const int m = mbase + wv * 16 + kh * 4 + rix;
        const int r = m >> 14, pix = m & (QN - 1);
        vhf[(size_t)((r * 8 + h) * QN + pix) * 32 + hd] = f2h16(acc[nt][rix] + bv);
      }
    }
    __syncthreads();
  }
}

// =============== K2: offsets + logits, BM=32 variant ============================
__global__ __launch_bounds__(256, 2) void k_gemm_oa(const float* __restrict__ A,
    const short* __restrict__ Bw, const float* __restrict__ boff,
    const float* __restrict__ battn, float* __restrict__ offw,
    float* __restrict__ logit){
  __shared__ short As[32 * 256];
  __shared__ short Bs[64 * 256];
  const int tid = threadIdx.x;
  const int lane = tid & 63, wv = tid >> 6;
  const int r16 = lane & 15, kh = lane >> 4;
  const int mg = wv & 1, ch = wv >> 1;
  const int swsel = (r16 & 7) << 4;
  const int mbase = blockIdx.x * 32;

  #pragma unroll
  for (int i = 0; i < 8; ++i){
    const int lin = i * 256 + tid;
    const int r = lin >> 6, ck = lin & 63;
    const f4_t v = *(const f4_t*)(A + (size_t)(mbase + r) * DK + ck * 4);
    s16x4 o = { f2bf(v[0]), f2bf(v[1]), f2bf(v[2]), f2bf(v[3]) };
    *(s16x4*)((char*)As + r * 512 + ((ck * 8) ^ ((r & 7) << 4))) = o;
  }
  s16x8 breg[8];
  #pragma unroll
  for (int i = 0; i < 8; ++i){
    const int lin = i * 256 + tid;
    const int n = lin >> 5, ck = lin & 31;
    breg[i] = *(const s16x8*)(Bw + (size_t)n * DK + ck * 8);
  }
  __syncthreads();

  for (int cg = 0; cg < 3; ++cg){
    #pragma unroll
    for (int i = 0; i < 8; ++i){
      const int lin = i * 256 + tid;
      const int n = lin >> 5, ck = lin & 31;
      *(s16x8*)((char*)Bs + n * 512 + ((ck * 16) ^ ((n & 7) << 4))) = breg[i];
    }
    __syncthreads();
    if (cg < 2){
      #pragma unroll
      for (int i = 0; i < 8; ++i){
        const int lin = i * 256 + tid;
        const int n = lin >> 5, ck = lin & 31;
        breg[i] = *(const s16x8*)(Bw + (size_t)((cg + 1) * 64 + n) * DK + ck * 8);
      }
    }
    f4_t acc[2];
    acc[0] = (f4_t){0.f,0.f,0.f,0.f}; acc[1] = (f4_t){0.f,0.f,0.f,0.f};
    #pragma unroll
    for (int kk = 0; kk < 8; ++kk){
      const int kb = kh * 16 + kk * 64;
      const s16x8 a = *(const s16x8*)((char*)As + (mg * 16 + r16) * 512 + (kb ^ swsel));
      #pragma unroll
      for (int nt = 0; nt < 2; ++nt){
        const s16x8 b = *(const s16x8*)((char*)Bs + (ch * 32 + nt * 16 + r16) * 512 + (kb ^ swsel));
        acc[nt] = __builtin_amdgcn_mfma_f32_16x16x32_bf16(a, b, acc[nt], 0, 0, 0);
      }
    }
    #pragma unroll
    for (int nt = 0; nt < 2; ++nt){
      const int n = cg * 64 + ch * 32 + nt * 16 + r16;
      #pragma unroll
      for (int rix = 0; rix < 4; ++rix){
        const int m = mbase + mg * 16 + kh * 4 + rix;
        const float v = acc[nt][rix];
        if (n < 128) offw[(size_t)m * 128 + n] = v + boff[n];
        else         logit[(size_t)m * 64 + (n - 128)] = v + battn[n - 128];
      }
    }
    __syncthreads();
  }
}

// =============== K4: output projection + bias + residual, BM=32 =================
__global__ __launch_bounds__(256, 2) void k_gemm_out(const float* __restrict__ A,
    const short* __restrict__ Bw, const float* __restrict__ bout,
    const float* __restrict__ query, float* __restrict__ out){
  __shared__ short As[32 * 256];
  __shared__ short Bs[64 * 256];
  const int tid = threadIdx.x;
  const int lane = tid & 63, wv = tid >> 6;
  const int r16 = lane & 15, kh = lane >> 4;
  const int mg = wv & 1, ch = wv >> 1;
  const int swsel = (r16 & 7) << 4;
  const int mbase = blockIdx.x * 32;

  #pragma unroll
  for (int i = 0; i < 8; ++i){
    const int lin = i * 256 + tid;
    const int r = lin >> 6, ck = lin & 63;
    const f4_t v = *(const f4_t*)(A + (size_t)(mbase + r) * DK + ck * 4);
    s16x4 o = { f2bf(v[0]), f2bf(v[1]), f2bf(v[2]), f2bf(v[3]) };
    *(s16x4*)((char*)As + r * 512 + ((ck * 8) ^ ((r & 7) << 4))) = o;
  }
  s16x8 breg[8];
  #pragma unroll
  for (int i = 0; i < 8; ++i){
    const int lin = i * 256 + tid;
    const int n = lin >> 5, ck = lin & 31;
    breg[i] = *(const s16x8*)(Bw + (size_t)n * DK + ck * 8);
  }
  __syncthreads();

  for (int cg = 0; cg < 4; ++cg){
    #pragma unroll
    for (int i = 0; i < 8; ++i){
      const int lin = i * 256 + tid;
      const int n = lin >> 5, ck = lin & 31;
      *(s16x8*)((char*)Bs + n * 512 + ((ck * 16) ^ ((n & 7) << 4))) = breg[i];
    }
    __syncthreads();
    if (cg < 3){
      #pragma unroll
      for (int i = 0; i < 8; ++i){
        const int lin = i * 256 + tid;
        const int n = lin >> 5, ck = lin & 31;
        breg[i] = *(const s16x8*)(Bw + (size_t)((cg + 1) * 64 + n) * DK + ck * 8);
      }
    }
    f4_t acc[2];
    acc[0] = (f4_t){0.f,0.f,0.f,0.f}; acc[1] = (f4_t){0.f,0.f,0.f,0.f};
    #pragma unroll
    for (int kk = 0; kk < 8; ++kk){
      const int kb = kh * 16 + kk * 64;
      const s16x8 a = *(const s16x8*)((char*)As + (mg * 16 + r16) * 512 + (kb ^ swsel));
      #pragma unroll
      for (int nt = 0; nt < 2; ++nt){
        const s16x8 b = *(const s16x8*)((char*)Bs + (ch * 32 + nt * 16 + r16) * 512 + (kb ^ swsel));
        acc[nt] = __builtin_amdgcn_mfma_f32_16x16x32_bf16(a, b, acc[nt], 0, 0, 0);
      }
    }
    #pragma unroll
    for (int nt = 0; nt < 2; ++nt){
      const int n = cg * 64 + ch * 32 + nt * 16 + r16;
      const float bo = bout[n];
      #pragma unroll
      for (int rix = 0; rix < 4; ++rix){
        const int m = mbase + mg * 16 + kh * 4 + rix;
        out[(size_t)m * DK + n] = acc[nt][rix] + bo + query[(size_t)m * DK + n];
      }
    }
    __syncthreads();
  }
}

// ---------------- K3: bilinear deformable sampling -------------------------------
// 4-lane group per query; lane j computes weights for its 4 of 16 samples and
// broadcasts 3 packed words/sample via __shfl. Inner loop = v_perm + v_dot2_f32_f16.
// NO arrays except statically-indexed acc[8]  (rule #20: avoid scratch).
__device__ inline void mkw(float rx, float ry, float ox, float oy, float awp,
                           u32& word, u32& pk01, u32& pk23){
  const float x = fmaf(rx, 128.f, ox) - 0.5f;
  const float y = fmaf(ry, 128.f, oy) - 0.5f;
  const float xf = floorf(x), yf = floorf(y);
  const float wx = x - xf, wy = y - yf;
  const int ix = (int)xf, iy = (int)yf;
  float xw0 = 1.f - wx, xw1 = wx, yw0 = 1.f - wy, yw1 = wy;
  if (ix < 0 || ix > 127)   xw0 = 0.f;
  if (ix < -1 || ix > 126)  xw1 = 0.f;
  if (iy < 0 || iy > 127)   yw0 = 0.f;
  if (iy < -1 || iy > 126)  yw1 = 0.f;
  const int ix0 = min(max(ix, 0), 127), ix1 = min(max(ix + 1, 0), 127);
  const int iy0 = min(max(iy, 0), 127), iy1 = min(max(iy + 1, 0), 127);
  const float t0 = awp * yw0, t1 = awp * yw1;
  pk01 = pk2h(t0 * xw0, t0 * xw1);
  pk23 = pk2h(t1 * xw0, t1 * xw1);
  word = (u32)(iy0 * 128 + ix0) | ((u32)(ix1 - ix0) << 16) | ((u32)(iy1 - iy0) << 17);
}

__global__ __launch_bounds__(256) void k_sampler(const float* __restrict__ rp,
    const float* __restrict__ offw, const float* __restrict__ logit,
    const short* __restrict__ vhf, float* __restrict__ O2){
  const int tid = threadIdx.x;
  const int j = tid & 3;
  const int grp = tid >> 2;
  const int lane = tid & 63;
  const int glane = lane & ~3;
  const int h = blockIdx.x & 7;
  const int q = (blockIdx.x >> 3) * 64 + grp;
  const u32 jof = (u32)j * 8;                 // fp16-element offset of this lane's slice

  // softmax over 8 logits (fold 0.5 mean-over-R); only aw[j], aw[j+4] kept
  const float* lp = logit + (size_t)q * 64 + h * 8;
  const float l0 = lp[0], l1 = lp[1], l2 = lp[2], l3 = lp[3];
  const float l4 = lp[4], l5 = lp[5], l6 = lp[6], l7 = lp[7];
  float mx = fmaxf(fmaxf(fmaxf(l0, l1), fmaxf(l2, l3)),
                   fmaxf(fmaxf(l4, l5), fmaxf(l6, l7)));
  float sum = __expf(l0 - mx) + __expf(l1 - mx) + __expf(l2 - mx) + __expf(l3 - mx)
            + __expf(l4 - mx) + __expf(l5 - mx) + __expf(l6 - mx) + __expf(l7 - mx);
  const float sc = 0.5f / sum;
  const float wA = __expf(lp[j] - mx) * sc;
  const float wB = __expf(lp[j + 4] - mx) * sc;

  // own offsets/refpoints: p = j and p = j+4 (za == j for both), r = 0 and 1
  const float* offp = offw + (size_t)q * 128 + h * 16;
  const float ox0 = offp[2 * j],     oy0 = offp[2 * j + 1];
  const float ox1 = offp[2 * j + 8], oy1 = offp[2 * j + 9];
  const float* rp0 = rp + (size_t)q * 8 + j * 2;
  const float* rp1 = rp + (size_t)(QN + q) * 8 + j * 2;
  const float rx0 = rp0[0], ry0 = rp0[1];
  const float rx1 = rp1[0], ry1 = rp1[1];

  // weights for my 4 samples, all in NAMED scalars (no arrays -> no scratch)
  u32 wrd0, pk01_0, pk23_0, wrd1, pk01_1, pk23_1;
  u32 wrd2, pk01_2, pk23_2, wrd3, pk01_3, pk23_3;
  mkw(rx0, ry0, ox0, oy0, wA, wrd0, pk01_0, pk23_0);   // k=0 -> (r=0, p=j)
  mkw(rx0, ry0, ox1, oy1, wB, wrd1, pk01_1, pk23_1);   // k=1 -> (r=0, p=j+4)
  mkw(rx1, ry1, ox0, oy0, wA, wrd2, pk01_2, pk23_2);   // k=2 -> (r=1, p=j)
  mkw(rx1, ry1, ox1, oy1, wB, wrd3, pk01_3, pk23_3);   // k=3 -> (r=1, p=j+4)

  const short* vb0 = vhf + (size_t)(h * QN) * 32;
  const short* vb1 = vhf + (size_t)((8 + h) * QN) * 32;

  float acc[8] = {0.f,0.f,0.f,0.f,0.f,0.f,0.f,0.f};

  // STEP(S): sample s = S; source lane = glane|(S&3); k = S>>2 named directly.
#define STEP(S, WRD, PK01, PK23) do{                                        \
    const int srcl_ = glane | ((S) & 3);                                    \
    const u32 w01_ = __shfl((PK01), srcl_);                                 \
    const u32 w23_ = __shfl((PK23), srcl_);                                 \
    const u32 wd_  = __shfl((WRD),  srcl_);                                 \
    const u32 o00_ = (wd_ & 0xFFFFu) * 32u + jof;                           \
    const u32 o01_ = o00_ + ((wd_ >> 11) & 32u);                            \
    const u32 dy_  = (wd_ >> 17) & 1u;                                      \
    const u32 o10_ = o00_ + dy_ * 4096u;                                    \
    const u32 o11_ = o01_ + dy_ * 4096u;                                    \
    const short* vb_ = ((S) >> 3) ? vb1 : vb0;                              \
    const u32x4 c00_ = *(const u32x4*)(vb_ + o00_);                         \
    const u32x4 c01_ = *(const u32x4*)(vb_ + o01_);                         \
    const u32x4 c10_ = *(const u32x4*)(vb_ + o10_);                         \
    const u32x4 c11_ = *(const u32x4*)(vb_ + o11_);                         \
    _Pragma("unroll")                                                       \
    for (int e = 0; e < 4; ++e){                                            \
      const u32 p0_ = bperm(c01_[e], c00_[e], 0x05040100u);                 \
      const u32 p1_ = bperm(c01_[e], c00_[e], 0x07060302u);                 \
      const u32 q0_ = bperm(c11_[e], c10_[e], 0x05040100u);                 \
      const u32 q1_ = bperm(c11_[e], c10_[e], 0x07060302u);                 \
      acc[2*e]   = dot2h(p0_, w01_, acc[2*e]);                              \
      acc[2*e+1] = dot2h(p1_, w01_, acc[2*e+1]);                            \
      acc[2*e]   = dot2h(q0_, w23_, acc[2*e]);                              \
      acc[2*e+1] = dot2h(q1_, w23_, acc[2*e+1]);                            \
    }                                                                       \
  }while(0)

  // samples 0..7: r=0 (k=0 for s<4, k=1 for s>=4); 8..15: r=1 (k=2,3)
  STEP(0,  wrd0, pk01_0, pk23_0); STEP(1,  wrd0, pk01_0, pk23_0);
  STEP(2,  wrd0, pk01_0, pk23_0); STEP(3,  wrd0, pk01_0, pk23_0);
  STEP(4,  wrd1, pk01_1, pk23_1); STEP(5,  wrd1, pk01_1, pk23_1);
  STEP(6,  wrd1, pk01_1, pk23_1); STEP(7,  wrd1, pk01_1, pk23_1);
  STEP(8,  wrd2, pk01_2, pk23_2); STEP(9,  wrd2, pk01_2, pk23_2);
  STEP(10, wrd2, pk01_2, pk23_2); STEP(11, wrd2, pk01_2, pk23_2);
  STEP(12, wrd3, pk01_3, pk23_3); STEP(13, wrd3, pk01_3, pk23_3);
  STEP(14, wrd3, pk01_3, pk23_3); STEP(15, wrd3, pk01_3, pk23_3);
#undef STEP

  float* op = O2 + (size_t)q * DK + h * 32 + j * 8;
  *(f4_t*)op       = (f4_t){acc[0], acc[1], acc[2], acc[3]};
  *(f4_t*)(op + 4) = (f4_t){acc[4], acc[5], acc[6], acc[7]};
}

extern "C" void kernel_launch(void* const* d_in, const int* in_sizes, int n_in,
                              void* d_out, int out_size, void* d_ws, size_t ws_size,
                              hipStream_t stream) {
  const float* query = (const float*)d_in[0];
  const float* value = (const float*)d_in[1];
  const float* refpt = (const float*)d_in[2];
  // d_in[3] spatial_shapes: fixed [[128,128]], hardcoded
  const float* W_off  = (const float*)d_in[4];
  const float* b_off  = (const float*)d_in[5];
  const float* W_attn = (const float*)d_in[6];
  const float* b_attn = (const float*)d_in[7];
  const float* W_val  = (const float*)d_in[8];
  const float* b_val  = (const float*)d_in[9];
  const float* W_out  = (const float*)d_in[10];
  const float* b_out  = (const float*)d_in[11];
  float* out = (float*)d_out;

  char* ws = (char*)d_ws;
  short* Wbf  = (short*)(ws);                    // 704*256 bf16          (360448 B)
  short* vhf  = (short*)(ws + 360448);           // 2*8*16384*32 fp16     (16777216 B)
  float* offw = (float*)(ws + 17137664);         // 16384*128 f32         (8388608 B)
  float* logit= (float*)(ws + 25526272);         // 16384*64 f32          (4194304 B)
  float* O2   = (float*)(ws + 29720576);         // 16384*256 f32         (16777216 B)

  k_convw   <<<dim3(704),  dim3(256), 0, stream>>>(W_val, W_off, W_attn, W_out, Wbf);
  k_gemm_val<<<dim3(512),  dim3(256), 0, stream>>>(value, Wbf, b_val, vhf);
  k_gemm_oa <<<dim3(512),  dim3(256), 0, stream>>>(query, Wbf + 256 * DK, b_off, b_attn, offw, logit);
  k_sampler <<<dim3(2048), dim3(256), 0, stream>>>(refpt, offw, logit, vhf, O2);
  k_gemm_out<<<dim3(512),  dim3(256), 0, stream>>>(O2, Wbf + 448 * DK, b_out, query, out);
}

// Round 7
// 75.634 us; speedup vs baseline: 3.9434x; 1.0494x over previous
//
#include <hip/hip_runtime.h>
#include <hip/hip_bf16.h>
#include <hip/hip_fp16.h>

// Problem constants: B=1,R=2,D=256,NH=8,NP=8,ZA=4,H=W=128,Q=16384,HD=32
#define QN 16384
#define DK 256

typedef float f4_t __attribute__((ext_vector_type(4)));
typedef short s16x8 __attribute__((ext_vector_type(8)));
typedef short s16x4 __attribute__((ext_vector_type(4)));
typedef unsigned int u32;
typedef u32 u32x4 __attribute__((ext_vector_type(4)));
typedef __fp16 h2_t __attribute__((ext_vector_type(2)));

__device__ inline short f2bf(float f){
  __hip_bfloat16 h = __float2bfloat16(f);
  return __builtin_bit_cast(short, h);
}
__device__ inline short f2h16(float f){
  __half h = __float2half(f);
  return __builtin_bit_cast(short, h);
}
__device__ inline float dot2h(u32 a, u32 b, float c){
#if __has_builtin(__builtin_amdgcn_fdot2)
  return __builtin_amdgcn_fdot2(__builtin_bit_cast(h2_t, a),
                                __builtin_bit_cast(h2_t, b), c, false);
#else
  h2_t ha = __builtin_bit_cast(h2_t, a), hb = __builtin_bit_cast(h2_t, b);
  return c + (float)ha[0] * (float)hb[0] + (float)ha[1] * (float)hb[1];
#endif
}
__device__ inline u32 pk2h(float a, float b){
#if __has_builtin(__builtin_amdgcn_cvt_pkrtz)
  h2_t r = __builtin_amdgcn_cvt_pkrtz(a, b);
  return __builtin_bit_cast(u32, r);
#else
  return (u32)__builtin_bit_cast(unsigned short, __float2half(a)) |
         ((u32)__builtin_bit_cast(unsigned short, __float2half(b)) << 16);
#endif
}
__device__ inline u32 bperm(u32 s0, u32 s1, u32 sel){
  // D.byte[i] = byte sel[i] of {S0:S1}: sel 0-3 -> S1 bytes, 4-7 -> S0 bytes.
  return __builtin_amdgcn_perm(s0, s1, sel);
}

// ---------------- weight pre-convert (f32 -> bf16, row-major K=256) -------------
// rows 0..255 = W_val, 256..383 = W_off, 384..447 = W_attn, 448..703 = W_out
__global__ __launch_bounds__(256) void k_convw(const float* __restrict__ Wv,
    const float* __restrict__ Woff, const float* __restrict__ Wattn,
    const float* __restrict__ Wout, short* __restrict__ Wbf){
  const int row = blockIdx.x;
  const int c = threadIdx.x;
  const float* src;
  if (row < 256)       src = Wv    + (size_t)row * DK;
  else if (row < 384)  src = Woff  + (size_t)(row - 256) * DK;
  else if (row < 448)  src = Wattn + (size_t)(row - 384) * DK;
  else                 src = Wout  + (size_t)(row - 448) * DK;
  Wbf[(size_t)row * DK + c] = f2bf(src[c]);
}

// =============== K1: value projection, LDS-staged MFMA GEMM =====================
// Output stored as FP16 (for the sampler's v_dot2_f32_f16 inner loop).
__global__ __launch_bounds__(256, 2) void k_gemm_val(const float* __restrict__ A,
    const short* __restrict__ Bw, const float* __restrict__ bval,
    short* __restrict__ vhf){
  __shared__ short As[64 * 256];
  __shared__ short Bs[64 * 256];
  const int tid = threadIdx.x;
  const int lane = tid & 63, wv = tid >> 6;
  const int r16 = lane & 15, kh = lane >> 4;
  const int swsel = (r16 & 7) << 4;
  const int mbase = blockIdx.x * 64;

  #pragma unroll
  for (int i = 0; i < 16; ++i){
    const int lin = i * 256 + tid;
    const int r = lin >> 6, ck = lin & 63;
    const f4_t v = *(const f4_t*)(A + (size_t)(mbase + r) * DK + ck * 4);
    s16x4 o = { f2bf(v[0]), f2bf(v[1]), f2bf(v[2]), f2bf(v[3]) };
    *(s16x4*)((char*)As + r * 512 + ((ck * 8) ^ ((r & 7) << 4))) = o;
  }
  s16x8 breg[8];
  #pragma unroll
  for (int i = 0; i < 8; ++i){
    const int lin = i * 256 + tid;
    const int n = lin >> 5, ck = lin & 31;
    breg[i] = *(const s16x8*)(Bw + (size_t)n * DK + ck * 8);
  }
  __syncthreads();

  for (int cg = 0; cg < 4; ++cg){
    #pragma unroll
    for (int i = 0; i < 8; ++i){
      const int lin = i * 256 + tid;
      const int n = lin >> 5, ck = lin & 31;
      *(s16x8*)((char*)Bs + n * 512 + ((ck * 16) ^ ((n & 7) << 4))) = breg[i];
    }
    __syncthreads();
    if (cg < 3){
      #pragma unroll
      for (int i = 0; i < 8; ++i){
        const int lin = i * 256 + tid;
        const int n = lin >> 5, ck = lin & 31;
        breg[i] = *(const s16x8*)(Bw + (size_t)((cg + 1) * 64 + n) * DK + ck * 8);
      }
    }
    f4_t acc[4];
    #pragma unroll
    for (int i = 0; i < 4; ++i) acc[i] = (f4_t){0.f, 0.f, 0.f, 0.f};
    #pragma unroll
    for (int kk = 0; kk < 8; ++kk){
      const int kb = kh * 16 + kk * 64;
      const s16x8 a = *(const s16x8*)((char*)As + (wv * 16 + r16) * 512 + (kb ^ swsel));
      #pragma unroll
      for (int nt = 0; nt < 4; ++nt){
        const s16x8 b = *(const s16x8*)((char*)Bs + (nt * 16 + r16) * 512 + (kb ^ swsel));
        acc[nt] = __builtin_amdgcn_mfma_f32_16x16x32_bf16(a, b, acc[nt], 0, 0, 0);
      }
    }
    #pragma unroll
    for (int nt = 0; nt < 4; ++nt){
      const int n = cg * 64 + nt * 16 + r16;
      const int h = n >> 5, hd = n & 31;
      const float bv = bval[n];
      #pragma unroll
      for (int rix = 0; rix < 4; ++rix){
        const int m = mbase + wv * 16 + kh * 4 + rix;
        const int r = m >> 14, pix = m & (QN - 1);
        vhf[(size_t)((r * 8 + h) * QN + pix) * 32 + hd] = f2h16(acc[nt][rix] + bv);
      }
    }
    __syncthreads();
  }
}

// =============== K2: offsets + logits, BM=32 variant ============================
__global__ __launch_bounds__(256, 2) void k_gemm_oa(const float* __restrict__ A,
    const short* __restrict__ Bw, const float* __restrict__ boff,
    const float* __restrict__ battn, float* __restrict__ offw,
    float* __restrict__ logit){
  __shared__ short As[32 * 256];
  __shared__ short Bs[64 * 256];
  const int tid = threadIdx.x;
  const int lane = tid & 63, wv = tid >> 6;
  const int r16 = lane & 15, kh = lane >> 4;
  const int mg = wv & 1, ch = wv >> 1;
  const int swsel = (r16 & 7) << 4;
  const int mbase = blockIdx.x * 32;

  #pragma unroll
  for (int i = 0; i < 8; ++i){
    const int lin = i * 256 + tid;
    const int r = lin >> 6, ck = lin & 63;
    const f4_t v = *(const f4_t*)(A + (size_t)(mbase + r) * DK + ck * 4);
    s16x4 o = { f2bf(v[0]), f2bf(v[1]), f2bf(v[2]), f2bf(v[3]) };
    *(s16x4*)((char*)As + r * 512 + ((ck * 8) ^ ((r & 7) << 4))) = o;
  }
  s16x8 breg[8];
  #pragma unroll
  for (int i = 0; i < 8; ++i){
    const int lin = i * 256 + tid;
    const int n = lin >> 5, ck = lin & 31;
    breg[i] = *(const s16x8*)(Bw + (size_t)n * DK + ck * 8);
  }
  __syncthreads();

  for (int cg = 0; cg < 3; ++cg){
    #pragma unroll
    for (int i = 0; i < 8; ++i){
      const int lin = i * 256 + tid;
      const int n = lin >> 5, ck = lin & 31;
      *(s16x8*)((char*)Bs + n * 512 + ((ck * 16) ^ ((n & 7) << 4))) = breg[i];
    }
    __syncthreads();
    if (cg < 2){
      #pragma unroll
      for (int i = 0; i < 8; ++i){
        const int lin = i * 256 + tid;
        const int n = lin >> 5, ck = lin & 31;
        breg[i] = *(const s16x8*)(Bw + (size_t)((cg + 1) * 64 + n) * DK + ck * 8);
      }
    }
    f4_t acc[2];
    acc[0] = (f4_t){0.f,0.f,0.f,0.f}; acc[1] = (f4_t){0.f,0.f,0.f,0.f};
    #pragma unroll
    for (int kk = 0; kk < 8; ++kk){
      const int kb = kh * 16 + kk * 64;
      const s16x8 a = *(const s16x8*)((char*)As + (mg * 16 + r16) * 512 + (kb ^ swsel));
      #pragma unroll
      for (int nt = 0; nt < 2; ++nt){
        const s16x8 b = *(const s16x8*)((char*)Bs + (ch * 32 + nt * 16 + r16) * 512 + (kb ^ swsel));
        acc[nt] = __builtin_amdgcn_mfma_f32_16x16x32_bf16(a, b, acc[nt], 0, 0, 0);
      }
    }
    #pragma unroll
    for (int nt = 0; nt < 2; ++nt){
      const int n = cg * 64 + ch * 32 + nt * 16 + r16;
      #pragma unroll
      for (int rix = 0; rix < 4; ++rix){
        const int m = mbase + mg * 16 + kh * 4 + rix;
        const float v = acc[nt][rix];
        if (n < 128) offw[(size_t)m * 128 + n] = v + boff[n];
        else         logit[(size_t)m * 64 + (n - 128)] = v + battn[n - 128];
      }
    }
    __syncthreads();
  }
}

// =============== K4: output projection + bias + residual, BM=32 =================
// A (=O2) is now bf16 row-major [16384][256] — staged directly, no conversion.
__global__ __launch_bounds__(256, 2) void k_gemm_out(const short* __restrict__ Ab,
    const short* __restrict__ Bw, const float* __restrict__ bout,
    const float* __restrict__ query, float* __restrict__ out){
  __shared__ short As[32 * 256];
  __shared__ short Bs[64 * 256];
  const int tid = threadIdx.x;
  const int lane = tid & 63, wv = tid >> 6;
  const int r16 = lane & 15, kh = lane >> 4;
  const int mg = wv & 1, ch = wv >> 1;
  const int swsel = (r16 & 7) << 4;
  const int mbase = blockIdx.x * 32;

  #pragma unroll
  for (int i = 0; i < 4; ++i){
    const int lin = i * 256 + tid;          // 16B chunk id: 32 rows x 32 chunks
    const int r = lin >> 5, ck = lin & 31;
    const s16x8 v = *(const s16x8*)(Ab + (size_t)(mbase + r) * DK + ck * 8);
    *(s16x8*)((char*)As + r * 512 + ((ck * 16) ^ ((r & 7) << 4))) = v;
  }
  s16x8 breg[8];
  #pragma unroll
  for (int i = 0; i < 8; ++i){
    const int lin = i * 256 + tid;
    const int n = lin >> 5, ck = lin & 31;
    breg[i] = *(const s16x8*)(Bw + (size_t)n * DK + ck * 8);
  }
  __syncthreads();

  for (int cg = 0; cg < 4; ++cg){
    #pragma unroll
    for (int i = 0; i < 8; ++i){
      const int lin = i * 256 + tid;
      const int n = lin >> 5, ck = lin & 31;
      *(s16x8*)((char*)Bs + n * 512 + ((ck * 16) ^ ((n & 7) << 4))) = breg[i];
    }
    __syncthreads();
    if (cg < 3){
      #pragma unroll
      for (int i = 0; i < 8; ++i){
        const int lin = i * 256 + tid;
        const int n = lin >> 5, ck = lin & 31;
        breg[i] = *(const s16x8*)(Bw + (size_t)((cg + 1) * 64 + n) * DK + ck * 8);
      }
    }
    f4_t acc[2];
    acc[0] = (f4_t){0.f,0.f,0.f,0.f}; acc[1] = (f4_t){0.f,0.f,0.f,0.f};
    #pragma unroll
    for (int kk = 0; kk < 8; ++kk){
      const int kb = kh * 16 + kk * 64;
      const s16x8 a = *(const s16x8*)((char*)As + (mg * 16 + r16) * 512 + (kb ^ swsel));
      #pragma unroll
      for (int nt = 0; nt < 2; ++nt){
        const s16x8 b = *(const s16x8*)((char*)Bs + (ch * 32 + nt * 16 + r16) * 512 + (kb ^ swsel));
        acc[nt] = __builtin_amdgcn_mfma_f32_16x16x32_bf16(a, b, acc[nt], 0, 0, 0);
      }
    }
    #pragma unroll
    for (int nt = 0; nt < 2; ++nt){
      const int n = cg * 64 + ch * 32 + nt * 16 + r16;
      const float bo = bout[n];
      #pragma unroll
      for (int rix = 0; rix < 4; ++rix){
        const int m = mbase + mg * 16 + kh * 4 + rix;
        out[(size_t)m * DK + n] = acc[nt][rix] + bo + query[(size_t)m * DK + n];
      }
    }
    __syncthreads();
  }
}

// ---------------- K3: bilinear sampling, 8-lane groups (row-pair loads) ---------
// Lane j3 = (px = j3>>2, cj = j3&3): pixel side x{0,1}, hd chunk [8cj,8cj+8).
// Per sample: 2 loads (row y0, row y1) instead of 4 — the group's 8 lanes cover
// both x-pixels' 128B contiguously (1 L2 line when x0 even -> 25% fewer requests).
// dot2 pairs (row0,row1) per hd channel; weights (t0*xw_px, t1*xw_px).
__device__ inline void mkw(float rx, float ry, float ox, float oy, float awp,
                           u32& word, u32& pk01, u32& pk23){
  const float x = fmaf(rx, 128.f, ox) - 0.5f;
  const float y = fmaf(ry, 128.f, oy) - 0.5f;
  const float xf = floorf(x), yf = floorf(y);
  const float wx = x - xf, wy = y - yf;
  const int ix = (int)xf, iy = (int)yf;
  float xw0 = 1.f - wx, xw1 = wx, yw0 = 1.f - wy, yw1 = wy;
  if (ix < 0 || ix > 127)   xw0 = 0.f;
  if (ix < -1 || ix > 126)  xw1 = 0.f;
  if (iy < 0 || iy > 127)   yw0 = 0.f;
  if (iy < -1 || iy > 126)  yw1 = 0.f;
  const int ix0 = min(max(ix, 0), 127), ix1 = min(max(ix + 1, 0), 127);
  const int iy0 = min(max(iy, 0), 127), iy1 = min(max(iy + 1, 0), 127);
  const float t0 = awp * yw0, t1 = awp * yw1;
  pk01 = pk2h(t0 * xw0, t0 * xw1);     // (row0: x0-weight, x1-weight)
  pk23 = pk2h(t1 * xw0, t1 * xw1);     // (row1: x0-weight, x1-weight)
  word = (u32)(iy0 * 128 + ix0) | ((u32)(ix1 - ix0) << 16) | ((u32)(iy1 - iy0) << 17);
}

__global__ __launch_bounds__(256) void k_sampler(const float* __restrict__ rp,
    const float* __restrict__ offw, const float* __restrict__ logit,
    const short* __restrict__ vhf, short* __restrict__ O2b){
  const int tid = threadIdx.x;
  const int j3 = tid & 7;               // lane in group
  const int cj = j3 & 3;                // hd chunk
  const int px = j3 >> 2;               // pixel side (x0 / x1)
  const int grp = tid >> 3;             // query in block: 0..31
  const int lane = tid & 63;
  const int glane8 = lane & ~7;
  const int h = blockIdx.x & 7;
  const int q = (blockIdx.x >> 3) * 32 + grp;
  const u32 cjof = (u32)cj * 8;
  const u32 selw = px ? 0x03020706u : 0x01000504u;   // pick my 16-bit halves

  // per-lane softmax weight for p = j3 (group shfl_xor reduce over 8 logits)
  const float* lp = logit + (size_t)q * 64 + h * 8;
  const float l = lp[j3];
  float m = l;
  m = fmaxf(m, __shfl_xor(m, 1)); m = fmaxf(m, __shfl_xor(m, 2)); m = fmaxf(m, __shfl_xor(m, 4));
  const float e = __expf(l - m);
  float ssum = e;
  ssum += __shfl_xor(ssum, 1); ssum += __shfl_xor(ssum, 2); ssum += __shfl_xor(ssum, 4);
  const float awp = e * (0.5f / ssum);

  // my point p = j3 (za = j3&3): offsets shared across r; rp differs per r
  const float* offp = offw + (size_t)q * 128 + h * 16;
  const float ox = offp[2 * j3], oy = offp[2 * j3 + 1];
  const int za2 = (j3 & 3) * 2;
  const float rx0 = rp[(size_t)q * 8 + za2],        ry0 = rp[(size_t)q * 8 + za2 + 1];
  const float rx1 = rp[(size_t)(QN + q) * 8 + za2], ry1 = rp[(size_t)(QN + q) * 8 + za2 + 1];

  u32 wrdA, pkA01, pkA23, wrdB, pkB01, pkB23;
  mkw(rx0, ry0, ox, oy, awp, wrdA, pkA01, pkA23);   // sample s = j3   (r=0)
  mkw(rx1, ry1, ox, oy, awp, wrdB, pkB01, pkB23);   // sample s = j3+8 (r=1)

  const short* vb0 = vhf + (size_t)(h * QN) * 32;
  const short* vb1 = vhf + (size_t)((8 + h) * QN) * 32;

  float acc[8] = {0.f,0.f,0.f,0.f,0.f,0.f,0.f,0.f};

#define STEP(S, WRD, PK01, PK23, VB) do{                                    \
    const int srcl_ = glane8 | ((S) & 7);                                   \
    const u32 wd_  = __shfl((WRD),  srcl_);                                 \
    const u32 w01_ = __shfl((PK01), srcl_);                                 \
    const u32 w23_ = __shfl((PK23), srcl_);                                 \
    const u32 wp_  = bperm(w01_, w23_, selw);  /* (t0*xw_px, t1*xw_px) */   \
    const u32 o0_  = (wd_ & 0xFFFFu) * 32u + cjof                           \
                   + (px ? ((wd_ >> 11) & 32u) : 0u);                       \
    const u32 o1_  = o0_ + ((wd_ >> 17) & 1u) * 4096u;                      \
    const u32x4 cA_ = *(const u32x4*)((VB) + o0_);   /* row y0 */           \
    const u32x4 cB_ = *(const u32x4*)((VB) + o1_);   /* row y1 */           \
    _Pragma("unroll")                                                       \
    for (int e_ = 0; e_ < 4; ++e_){                                         \
      const u32 pl_ = bperm(cA_[e_], cB_[e_], 0x01000504u);                 \
      const u32 ph_ = bperm(cA_[e_], cB_[e_], 0x03020706u);                 \
      acc[2*e_]   = dot2h(pl_, wp_, acc[2*e_]);                             \
      acc[2*e_+1] = dot2h(ph_, wp_, acc[2*e_+1]);                           \
    }                                                                       \
  }while(0)

  STEP(0,  wrdA, pkA01, pkA23, vb0); STEP(1,  wrdA, pkA01, pkA23, vb0);
  STEP(2,  wrdA, pkA01, pkA23, vb0); STEP(3,  wrdA, pkA01, pkA23, vb0);
  STEP(4,  wrdA, pkA01, pkA23, vb0); STEP(5,  wrdA, pkA01, pkA23, vb0);
  STEP(6,  wrdA, pkA01, pkA23, vb0); STEP(7,  wrdA, pkA01, pkA23, vb0);
  STEP(8,  wrdB, pkB01, pkB23, vb1); STEP(9,  wrdB, pkB01, pkB23, vb1);
  STEP(10, wrdB, pkB01, pkB23, vb1); STEP(11, wrdB, pkB01, pkB23, vb1);
  STEP(12, wrdB, pkB01, pkB23, vb1); STEP(13, wrdB, pkB01, pkB23, vb1);
  STEP(14, wrdB, pkB01, pkB23, vb1); STEP(15, wrdB, pkB01, pkB23, vb1);
#undef STEP

  // combine pixel-side partials (px=0 + px=1), write bf16 O2
  #pragma unroll
  for (int i = 0; i < 8; ++i) acc[i] += __shfl_xor(acc[i], 4);
  if (px == 0){
    s16x8 o = { f2bf(acc[0]), f2bf(acc[1]), f2bf(acc[2]), f2bf(acc[3]),
                f2bf(acc[4]), f2bf(acc[5]), f2bf(acc[6]), f2bf(acc[7]) };
    *(s16x8*)(O2b + (size_t)q * DK + h * 32 + cj * 8) = o;
  }
}

extern "C" void kernel_launch(void* const* d_in, const int* in_sizes, int n_in,
                              void* d_out, int out_size, void* d_ws, size_t ws_size,
                              hipStream_t stream) {
  const float* query = (const float*)d_in[0];
  const float* value = (const float*)d_in[1];
  const float* refpt = (const float*)d_in[2];
  // d_in[3] spatial_shapes: fixed [[128,128]], hardcoded
  const float* W_off  = (const float*)d_in[4];
  const float* b_off  = (const float*)d_in[5];
  const float* W_attn = (const float*)d_in[6];
  const float* b_attn = (const float*)d_in[7];
  const float* W_val  = (const float*)d_in[8];
  const float* b_val  = (const float*)d_in[9];
  const float* W_out  = (const float*)d_in[10];
  const float* b_out  = (const float*)d_in[11];
  float* out = (float*)d_out;

  char* ws = (char*)d_ws;
  short* Wbf  = (short*)(ws);                    // 704*256 bf16          (360448 B)
  short* vhf  = (short*)(ws + 360448);           // 2*8*16384*32 fp16     (16777216 B)
  float* offw = (float*)(ws + 17137664);         // 16384*128 f32         (8388608 B)
  float* logit= (float*)(ws + 25526272);         // 16384*64 f32          (4194304 B)
  short* O2b  = (short*)(ws + 29720576);         // 16384*256 bf16        (8388608 B)

  k_convw   <<<dim3(704),  dim3(256), 0, stream>>>(W_val, W_off, W_attn, W_out, Wbf);
  k_gemm_val<<<dim3(512),  dim3(256), 0, stream>>>(value, Wbf, b_val, vhf);
  k_gemm_oa <<<dim3(512),  dim3(256), 0, stream>>>(query, Wbf + 256 * DK, b_off, b_attn, offw, logit);
  k_sampler <<<dim3(4096), dim3(256), 0, stream>>>(refpt, offw, logit, vhf, O2b);
  k_gemm_out<<<dim3(512),  dim3(256), 0, stream>>>(O2b, Wbf + 448 * DK, b_out, query, out);
}

// Round 8
// 71.878 us; speedup vs baseline: 4.1494x; 1.0522x over previous
//
#include <hip/hip_runtime.h>
#include <hip/hip_bf16.h>
#include <hip/hip_fp16.h>

// Problem constants: B=1,R=2,D=256,NH=8,NP=8,ZA=4,H=W=128,Q=16384,HD=32
#define QN 16384
#define DK 256

typedef float f4_t __attribute__((ext_vector_type(4)));
typedef short s16x8 __attribute__((ext_vector_type(8)));
typedef short s16x4 __attribute__((ext_vector_type(4)));
typedef unsigned int u32;
typedef u32 u32x4 __attribute__((ext_vector_type(4)));
typedef __fp16 h2_t __attribute__((ext_vector_type(2)));

__device__ inline short f2bf(float f){
  __hip_bfloat16 h = __float2bfloat16(f);
  return __builtin_bit_cast(short, h);
}
__device__ inline short f2h16(float f){
  __half h = __float2half(f);
  return __builtin_bit_cast(short, h);
}
__device__ inline float dot2h(u32 a, u32 b, float c){
#if __has_builtin(__builtin_amdgcn_fdot2)
  return __builtin_amdgcn_fdot2(__builtin_bit_cast(h2_t, a),
                                __builtin_bit_cast(h2_t, b), c, false);
#else
  h2_t ha = __builtin_bit_cast(h2_t, a), hb = __builtin_bit_cast(h2_t, b);
  return c + (float)ha[0] * (float)hb[0] + (float)ha[1] * (float)hb[1];
#endif
}
__device__ inline u32 pk2h(float a, float b){
#if __has_builtin(__builtin_amdgcn_cvt_pkrtz)
  h2_t r = __builtin_amdgcn_cvt_pkrtz(a, b);
  return __builtin_bit_cast(u32, r);
#else
  return (u32)__builtin_bit_cast(unsigned short, __float2half(a)) |
         ((u32)__builtin_bit_cast(unsigned short, __float2half(b)) << 16);
#endif
}
__device__ inline u32 bperm(u32 s0, u32 s1, u32 sel){
  // D.byte[i] = byte sel[i] of {S0:S1}: sel 0-3 -> S1 bytes, 4-7 -> S0 bytes.
  return __builtin_amdgcn_perm(s0, s1, sel);
}

// ---------------- weight pre-convert (f32 -> bf16), vectorized ------------------
// 704 rows x 256 cols = 180224 elems; 44 blocks x 256 thr x 16 elems.
__global__ __launch_bounds__(256) void k_convw(const float* __restrict__ Wv,
    const float* __restrict__ Woff, const float* __restrict__ Wattn,
    const float* __restrict__ Wout, short* __restrict__ Wbf){
  const int base = (blockIdx.x * 256 + threadIdx.x) * 16;   // element index
  #pragma unroll
  for (int c = 0; c < 4; ++c){
    const int e = base + c * 4;
    const int row = e >> 8, col = e & 255;
    const float* src;
    int r = row;
    if (row < 256)       src = Wv    + (size_t)r * DK;
    else if (row < 384){ src = Woff  + (size_t)(r - 256) * DK; }
    else if (row < 448){ src = Wattn + (size_t)(r - 384) * DK; }
    else               { src = Wout  + (size_t)(r - 448) * DK; }
    const f4_t v = *(const f4_t*)(src + col);
    s16x4 o = { f2bf(v[0]), f2bf(v[1]), f2bf(v[2]), f2bf(v[3]) };
    *(s16x4*)(Wbf + e) = o;
  }
}

// =============== K1: fused projection GEMM ======================================
// bid < 512:  value-proj tile (BM=64, out fp16 gather layout vhf)
// bid >= 512: offset/logit tile (BM=32, out offw/logit f32)
__global__ __launch_bounds__(256, 2) void k_proj(const float* __restrict__ value,
    const float* __restrict__ query, const short* __restrict__ Wbf,
    const float* __restrict__ bval, const float* __restrict__ boff,
    const float* __restrict__ battn, short* __restrict__ vhf,
    float* __restrict__ offw, float* __restrict__ logit){
  __shared__ short As[64 * 256];
  __shared__ short Bs[64 * 256];
  const int tid = threadIdx.x;
  const int lane = tid & 63, wv = tid >> 6;
  const int r16 = lane & 15, kh = lane >> 4;
  const int swsel = (r16 & 7) << 4;
  const int bid = blockIdx.x;

  if (bid < 512){
    // ---------------- value-projection path (BM=64) ----------------
    const float* A = value;
    const short* Bw = Wbf;                       // W_val rows 0..255
    const int mbase = bid * 64;
    #pragma unroll
    for (int i = 0; i < 16; ++i){
      const int lin = i * 256 + tid;
      const int r = lin >> 6, ck = lin & 63;
      const f4_t v = *(const f4_t*)(A + (size_t)(mbase + r) * DK + ck * 4);
      s16x4 o = { f2bf(v[0]), f2bf(v[1]), f2bf(v[2]), f2bf(v[3]) };
      *(s16x4*)((char*)As + r * 512 + ((ck * 8) ^ ((r & 7) << 4))) = o;
    }
    s16x8 breg[8];
    #pragma unroll
    for (int i = 0; i < 8; ++i){
      const int lin = i * 256 + tid;
      const int n = lin >> 5, ck = lin & 31;
      breg[i] = *(const s16x8*)(Bw + (size_t)n * DK + ck * 8);
    }
    __syncthreads();
    for (int cg = 0; cg < 4; ++cg){
      #pragma unroll
      for (int i = 0; i < 8; ++i){
        const int lin = i * 256 + tid;
        const int n = lin >> 5, ck = lin & 31;
        *(s16x8*)((char*)Bs + n * 512 + ((ck * 16) ^ ((n & 7) << 4))) = breg[i];
      }
      __syncthreads();
      if (cg < 3){
        #pragma unroll
        for (int i = 0; i < 8; ++i){
          const int lin = i * 256 + tid;
          const int n = lin >> 5, ck = lin & 31;
          breg[i] = *(const s16x8*)(Bw + (size_t)((cg + 1) * 64 + n) * DK + ck * 8);
        }
      }
      f4_t acc[4];
      #pragma unroll
      for (int i = 0; i < 4; ++i) acc[i] = (f4_t){0.f, 0.f, 0.f, 0.f};
      #pragma unroll
      for (int kk = 0; kk < 8; ++kk){
        const int kb = kh * 16 + kk * 64;
        const s16x8 a = *(const s16x8*)((char*)As + (wv * 16 + r16) * 512 + (kb ^ swsel));
        #pragma unroll
        for (int nt = 0; nt < 4; ++nt){
          const s16x8 b = *(const s16x8*)((char*)Bs + (nt * 16 + r16) * 512 + (kb ^ swsel));
          acc[nt] = __builtin_amdgcn_mfma_f32_16x16x32_bf16(a, b, acc[nt], 0, 0, 0);
        }
      }
      #pragma unroll
      for (int nt = 0; nt < 4; ++nt){
        const int n = cg * 64 + nt * 16 + r16;
        const int h = n >> 5, hd = n & 31;
        const float bv = bval[n];
        #pragma unroll
        for (int rix = 0; rix < 4; ++rix){
          const int m = mbase + wv * 16 + kh * 4 + rix;
          const int r = m >> 14, pix = m & (QN - 1);
          vhf[(size_t)((r * 8 + h) * QN + pix) * 32 + hd] = f2h16(acc[nt][rix] + bv);
        }
      }
      __syncthreads();
    }
  } else {
    // ---------------- offset/logit path (BM=32) ----------------
    const float* A = query;
    const short* Bw = Wbf + 256 * DK;            // W_off|W_attn rows
    const int mg = wv & 1, ch = wv >> 1;
    const int mbase = (bid - 512) * 32;
    #pragma unroll
    for (int i = 0; i < 8; ++i){
      const int lin = i * 256 + tid;
      const int r = lin >> 6, ck = lin & 63;
      const f4_t v = *(const f4_t*)(A + (size_t)(mbase + r) * DK + ck * 4);
      s16x4 o = { f2bf(v[0]), f2bf(v[1]), f2bf(v[2]), f2bf(v[3]) };
      *(s16x4*)((char*)As + r * 512 + ((ck * 8) ^ ((r & 7) << 4))) = o;
    }
    s16x8 breg[8];
    #pragma unroll
    for (int i = 0; i < 8; ++i){
      const int lin = i * 256 + tid;
      const int n = lin >> 5, ck = lin & 31;
      breg[i] = *(const s16x8*)(Bw + (size_t)n * DK + ck * 8);
    }
    __syncthreads();
    for (int cg = 0; cg < 3; ++cg){
      #pragma unroll
      for (int i = 0; i < 8; ++i){
        const int lin = i * 256 + tid;
        const int n = lin >> 5, ck = lin & 31;
        *(s16x8*)((char*)Bs + n * 512 + ((ck * 16) ^ ((n & 7) << 4))) = breg[i];
      }
      __syncthreads();
      if (cg < 2){
        #pragma unroll
        for (int i = 0; i < 8; ++i){
          const int lin = i * 256 + tid;
          const int n = lin >> 5, ck = lin & 31;
          breg[i] = *(const s16x8*)(Bw + (size_t)((cg + 1) * 64 + n) * DK + ck * 8);
        }
      }
      f4_t acc[2];
      acc[0] = (f4_t){0.f,0.f,0.f,0.f}; acc[1] = (f4_t){0.f,0.f,0.f,0.f};
      #pragma unroll
      for (int kk = 0; kk < 8; ++kk){
        const int kb = kh * 16 + kk * 64;
        const s16x8 a = *(const s16x8*)((char*)As + (mg * 16 + r16) * 512 + (kb ^ swsel));
        #pragma unroll
        for (int nt = 0; nt < 2; ++nt){
          const s16x8 b = *(const s16x8*)((char*)Bs + (ch * 32 + nt * 16 + r16) * 512 + (kb ^ swsel));
          acc[nt] = __builtin_amdgcn_mfma_f32_16x16x32_bf16(a, b, acc[nt], 0, 0, 0);
        }
      }
      #pragma unroll
      for (int nt = 0; nt < 2; ++nt){
        const int n = cg * 64 + ch * 32 + nt * 16 + r16;
        #pragma unroll
        for (int rix = 0; rix < 4; ++rix){
          const int m = mbase + mg * 16 + kh * 4 + rix;
          const float v = acc[nt][rix];
          if (n < 128) offw[(size_t)m * 128 + n] = v + boff[n];
          else         logit[(size_t)m * 64 + (n - 128)] = v + battn[n - 128];
        }
      }
      __syncthreads();
    }
  }
}

// =============== K4: output projection + bias + residual, BM=32 =================
// A (=O2) is bf16 row-major [16384][256].
__global__ __launch_bounds__(256, 2) void k_gemm_out(const short* __restrict__ Ab,
    const short* __restrict__ Bw, const float* __restrict__ bout,
    const float* __restrict__ query, float* __restrict__ out){
  __shared__ short As[32 * 256];
  __shared__ short Bs[64 * 256];
  const int tid = threadIdx.x;
  const int lane = tid & 63, wv = tid >> 6;
  const int r16 = lane & 15, kh = lane >> 4;
  const int mg = wv & 1, ch = wv >> 1;
  const int swsel = (r16 & 7) << 4;
  const int mbase = blockIdx.x * 32;

  #pragma unroll
  for (int i = 0; i < 4; ++i){
    const int lin = i * 256 + tid;          // 16B chunk id: 32 rows x 32 chunks
    const int r = lin >> 5, ck = lin & 31;
    const s16x8 v = *(const s16x8*)(Ab + (size_t)(mbase + r) * DK + ck * 8);
    *(s16x8*)((char*)As + r * 512 + ((ck * 16) ^ ((r & 7) << 4))) = v;
  }
  s16x8 breg[8];
  #pragma unroll
  for (int i = 0; i < 8; ++i){
    const int lin = i * 256 + tid;
    const int n = lin >> 5, ck = lin & 31;
    breg[i] = *(const s16x8*)(Bw + (size_t)n * DK + ck * 8);
  }
  __syncthreads();

  for (int cg = 0; cg < 4; ++cg){
    #pragma unroll
    for (int i = 0; i < 8; ++i){
      const int lin = i * 256 + tid;
      const int n = lin >> 5, ck = lin & 31;
      *(s16x8*)((char*)Bs + n * 512 + ((ck * 16) ^ ((n & 7) << 4))) = breg[i];
    }
    __syncthreads();
    if (cg < 3){
      #pragma unroll
      for (int i = 0; i < 8; ++i){
        const int lin = i * 256 + tid;
        const int n = lin >> 5, ck = lin & 31;
        breg[i] = *(const s16x8*)(Bw + (size_t)((cg + 1) * 64 + n) * DK + ck * 8);
      }
    }
    f4_t acc[2];
    acc[0] = (f4_t){0.f,0.f,0.f,0.f}; acc[1] = (f4_t){0.f,0.f,0.f,0.f};
    #pragma unroll
    for (int kk = 0; kk < 8; ++kk){
      const int kb = kh * 16 + kk * 64;
      const s16x8 a = *(const s16x8*)((char*)As + (mg * 16 + r16) * 512 + (kb ^ swsel));
      #pragma unroll
      for (int nt = 0; nt < 2; ++nt){
        const s16x8 b = *(const s16x8*)((char*)Bs + (ch * 32 + nt * 16 + r16) * 512 + (kb ^ swsel));
        acc[nt] = __builtin_amdgcn_mfma_f32_16x16x32_bf16(a, b, acc[nt], 0, 0, 0);
      }
    }
    #pragma unroll
    for (int nt = 0; nt < 2; ++nt){
      const int n = cg * 64 + ch * 32 + nt * 16 + r16;
      const float bo = bout[n];
      #pragma unroll
      for (int rix = 0; rix < 4; ++rix){
        const int m = mbase + mg * 16 + kh * 4 + rix;
        out[(size_t)m * DK + n] = acc[nt][rix] + bo + query[(size_t)m * DK + n];
      }
    }
    __syncthreads();
  }
}

// ---------------- K3: bilinear sampling, 8-lane groups, 3-deep pipeline ---------
__device__ inline void mkw(float rx, float ry, float ox, float oy, float awp,
                           u32& word, u32& pk01, u32& pk23){
  const float x = fmaf(rx, 128.f, ox) - 0.5f;
  const float y = fmaf(ry, 128.f, oy) - 0.5f;
  const float xf = floorf(x), yf = floorf(y);
  const float wx = x - xf, wy = y - yf;
  const int ix = (int)xf, iy = (int)yf;
  float xw0 = 1.f - wx, xw1 = wx, yw0 = 1.f - wy, yw1 = wy;
  if (ix < 0 || ix > 127)   xw0 = 0.f;
  if (ix < -1 || ix > 126)  xw1 = 0.f;
  if (iy < 0 || iy > 127)   yw0 = 0.f;
  if (iy < -1 || iy > 126)  yw1 = 0.f;
  const int ix0 = min(max(ix, 0), 127), ix1 = min(max(ix + 1, 0), 127);
  const int iy0 = min(max(iy, 0), 127), iy1 = min(max(iy + 1, 0), 127);
  const float t0 = awp * yw0, t1 = awp * yw1;
  pk01 = pk2h(t0 * xw0, t0 * xw1);     // (row0: x0-w, x1-w)
  pk23 = pk2h(t1 * xw0, t1 * xw1);     // (row1: x0-w, x1-w)
  word = (u32)(iy0 * 128 + ix0) | ((u32)(ix1 - ix0) << 16) | ((u32)(iy1 - iy0) << 17);
}

__global__ __launch_bounds__(256) void k_sampler(const float* __restrict__ rp,
    const float* __restrict__ offw, const float* __restrict__ logit,
    const short* __restrict__ vhf, short* __restrict__ O2b){
  const int tid = threadIdx.x;
  const int j3 = tid & 7;               // lane in group
  const int cj = j3 & 3;                // hd chunk
  const int px = j3 >> 2;               // pixel side (x0 / x1)
  const int grp = tid >> 3;             // query in block: 0..31
  const int lane = tid & 63;
  const int glane8 = lane & ~7;
  const int h = blockIdx.x & 7;
  const int q = (blockIdx.x >> 3) * 32 + grp;
  const u32 cjof = (u32)cj * 8;
  const u32 selw = px ? 0x03020706u : 0x01000504u;

  // per-lane softmax weight for p = j3 (8-lane shfl_xor reduce)
  const float* lp = logit + (size_t)q * 64 + h * 8;
  const float l = lp[j3];
  float m = l;
  m = fmaxf(m, __shfl_xor(m, 1)); m = fmaxf(m, __shfl_xor(m, 2)); m = fmaxf(m, __shfl_xor(m, 4));
  const float e = __expf(l - m);
  float ssum = e;
  ssum += __shfl_xor(ssum, 1); ssum += __shfl_xor(ssum, 2); ssum += __shfl_xor(ssum, 4);
  const float awp = e * (0.5f / ssum);

  const float* offp = offw + (size_t)q * 128 + h * 16;
  const float ox = offp[2 * j3], oy = offp[2 * j3 + 1];
  const int za2 = (j3 & 3) * 2;
  const float rx0 = rp[(size_t)q * 8 + za2],        ry0 = rp[(size_t)q * 8 + za2 + 1];
  const float rx1 = rp[(size_t)(QN + q) * 8 + za2], ry1 = rp[(size_t)(QN + q) * 8 + za2 + 1];

  u32 wrdA, pkA01, pkA23, wrdB, pkB01, pkB23;
  mkw(rx0, ry0, ox, oy, awp, wrdA, pkA01, pkA23);   // r=0 sample
  mkw(rx1, ry1, ox, oy, awp, wrdB, pkB01, pkB23);   // r=1 sample

  const short* vb0 = vhf + (size_t)(h * QN) * 32;
  const short* vb1 = vhf + (size_t)((8 + h) * QN) * 32;

  float acc[8] = {0.f,0.f,0.f,0.f,0.f,0.f,0.f,0.f};

  // LOADP declares named step-local corner regs; USEP consumes them.
#define LOADP(S, WRD, VB)                                                   \
  const u32 wd_##S = __shfl((WRD), glane8 | ((S) & 7));                     \
  const u32 o0_##S = (wd_##S & 0xFFFFu) * 32u + cjof                        \
                   + (px ? ((wd_##S >> 11) & 32u) : 0u);                    \
  const u32 o1_##S = o0_##S + ((wd_##S >> 17) & 1u) * 4096u;                \
  const u32x4 cA_##S = *(const u32x4*)((VB) + o0_##S);                      \
  const u32x4 cB_##S = *(const u32x4*)((VB) + o1_##S);

#define USEP(S, PK01, PK23) do{                                             \
    const int srcl_ = glane8 | ((S) & 7);                                   \
    const u32 w01_ = __shfl((PK01), srcl_);                                 \
    const u32 w23_ = __shfl((PK23), srcl_);                                 \
    const u32 wp_  = bperm(w01_, w23_, selw);                               \
    _Pragma("unroll")                                                       \
    for (int e_ = 0; e_ < 4; ++e_){                                         \
      const u32 pl_ = bperm(cA_##S[e_], cB_##S[e_], 0x01000504u);           \
      const u32 ph_ = bperm(cA_##S[e_], cB_##S[e_], 0x03020706u);           \
      acc[2*e_]   = dot2h(pl_, wp_, acc[2*e_]);                             \
      acc[2*e_+1] = dot2h(ph_, wp_, acc[2*e_+1]);                           \
    }                                                                       \
  }while(0)

  LOADP(0,  wrdA, vb0) LOADP(1,  wrdA, vb0) LOADP(2,  wrdA, vb0)
  USEP(0,  pkA01, pkA23); LOADP(3,  wrdA, vb0)
  USEP(1,  pkA01, pkA23); LOADP(4,  wrdA, vb0)
  USEP(2,  pkA01, pkA23); LOADP(5,  wrdA, vb0)
  USEP(3,  pkA01, pkA23); LOADP(6,  wrdA, vb0)
  USEP(4,  pkA01, pkA23); LOADP(7,  wrdA, vb0)
  USEP(5,  pkA01, pkA23); LOADP(8,  wrdB, vb1)
  USEP(6,  pkA01, pkA23); LOADP(9,  wrdB, vb1)
  USEP(7,  pkA01, pkA23); LOADP(10, wrdB, vb1)
  USEP(8,  pkB01, pkB23); LOADP(11, wrdB, vb1)
  USEP(9,  pkB01, pkB23); LOADP(12, wrdB, vb1)
  USEP(10, pkB01, pkB23); LOADP(13, wrdB, vb1)
  USEP(11, pkB01, pkB23); LOADP(14, wrdB, vb1)
  USEP(12, pkB01, pkB23); LOADP(15, wrdB, vb1)
  USEP(13, pkB01, pkB23);
  USEP(14, pkB01, pkB23);
  USEP(15, pkB01, pkB23);
#undef LOADP
#undef USEP

  // combine pixel-side partials (px=0 + px=1), write bf16 O2
  #pragma unroll
  for (int i = 0; i < 8; ++i) acc[i] += __shfl_xor(acc[i], 4);
  if (px == 0){
    s16x8 o = { f2bf(acc[0]), f2bf(acc[1]), f2bf(acc[2]), f2bf(acc[3]),
                f2bf(acc[4]), f2bf(acc[5]), f2bf(acc[6]), f2bf(acc[7]) };
    *(s16x8*)(O2b + (size_t)q * DK + h * 32 + cj * 8) = o;
  }
}

extern "C" void kernel_launch(void* const* d_in, const int* in_sizes, int n_in,
                              void* d_out, int out_size, void* d_ws, size_t ws_size,
                              hipStream_t stream) {
  const float* query = (const float*)d_in[0];
  const float* value = (const float*)d_in[1];
  const float* refpt = (const float*)d_in[2];
  // d_in[3] spatial_shapes: fixed [[128,128]], hardcoded
  const float* W_off  = (const float*)d_in[4];
  const float* b_off  = (const float*)d_in[5];
  const float* W_attn = (const float*)d_in[6];
  const float* b_attn = (const float*)d_in[7];
  const float* W_val  = (const float*)d_in[8];
  const float* b_val  = (const float*)d_in[9];
  const float* W_out  = (const float*)d_in[10];
  const float* b_out  = (const float*)d_in[11];
  float* out = (float*)d_out;

  char* ws = (char*)d_ws;
  short* Wbf  = (short*)(ws);                    // 704*256 bf16          (360448 B)
  short* vhf  = (short*)(ws + 360448);           // 2*8*16384*32 fp16     (16777216 B)
  float* offw = (float*)(ws + 17137664);         // 16384*128 f32         (8388608 B)
  float* logit= (float*)(ws + 25526272);         // 16384*64 f32          (4194304 B)
  short* O2b  = (short*)(ws + 29720576);         // 16384*256 bf16        (8388608 B)

  k_convw   <<<dim3(44),   dim3(256), 0, stream>>>(W_val, W_off, W_attn, W_out, Wbf);
  k_proj    <<<dim3(1024), dim3(256), 0, stream>>>(value, query, Wbf, b_val, b_off,
                                                   b_attn, vhf, offw, logit);
  k_sampler <<<dim3(4096), dim3(256), 0, stream>>>(refpt, offw, logit, vhf, O2b);
  k_gemm_out<<<dim3(512),  dim3(256), 0, stream>>>(O2b, Wbf + 448 * DK, b_out, query, out);
}

// Round 10
// 67.844 us; speedup vs baseline: 4.3962x; 1.0595x over previous
//
#include <hip/hip_runtime.h>
#include <hip/hip_bf16.h>
#include <hip/hip_fp16.h>
#include <hip/hip_fp8.h>

// Problem constants: B=1,R=2,D=256,NH=8,NP=8,ZA=4,H=W=128,Q=16384,HD=32
#define QN 16384
#define DK 256

typedef float f4_t __attribute__((ext_vector_type(4)));
typedef float f2_t __attribute__((ext_vector_type(2)));
typedef short s16x8 __attribute__((ext_vector_type(8)));
typedef short s16x4 __attribute__((ext_vector_type(4)));
typedef unsigned int u32;
typedef u32 u32x4 __attribute__((ext_vector_type(4)));
typedef u32 u32x2 __attribute__((ext_vector_type(2)));
typedef __fp16 h2_t __attribute__((ext_vector_type(2)));

__device__ inline short f2bf(float f){
  __hip_bfloat16 h = __float2bfloat16(f);
  return __builtin_bit_cast(short, h);
}
__device__ inline u32 pk2h(float a, float b){
#if __has_builtin(__builtin_amdgcn_cvt_pkrtz)
  h2_t r = __builtin_amdgcn_cvt_pkrtz(a, b);
  return __builtin_bit_cast(u32, r);
#else
  return (u32)__builtin_bit_cast(unsigned short, __float2half(a)) |
         ((u32)__builtin_bit_cast(unsigned short, __float2half(b)) << 16);
#endif
}
__device__ inline u32 bperm(u32 s0, u32 s1, u32 sel){
  return __builtin_amdgcn_perm(s0, s1, sel);
}
// fp8 e4m3 pack (2 floats -> low 16 bits) / unpack (HI selects byte-pair), HI is
// a TEMPLATE arg because the builtin requires an immediate selector.
__device__ inline u32 pk_fp8(float a, float b){
#if __has_builtin(__builtin_amdgcn_cvt_pk_fp8_f32)
  return (u32)__builtin_amdgcn_cvt_pk_fp8_f32(a, b, 0, false);
#else
  __hip_fp8_e4m3 fa(a), fb(b);
  return (u32)fa.__x | ((u32)fb.__x << 8);
#endif
}
template<bool HI>
__device__ inline f2_t upk_fp8(u32 w){
#if __has_builtin(__builtin_amdgcn_cvt_pk_f32_fp8)
  return __builtin_amdgcn_cvt_pk_f32_fp8(w, HI);
#else
  const u32 hh = HI ? (w >> 16) : (w & 0xFFFFu);
  __hip_fp8_e4m3 a, b;
  a.__x = (unsigned char)(hh & 0xFF);
  b.__x = (unsigned char)(hh >> 8);
  return (f2_t){(float)a, (float)b};
#endif
}

// ---------------- weight pre-convert (f32 -> bf16), vectorized ------------------
__global__ __launch_bounds__(256) void k_convw(const float* __restrict__ Wv,
    const float* __restrict__ Woff, const float* __restrict__ Wattn,
    const float* __restrict__ Wout, short* __restrict__ Wbf){
  const int base = (blockIdx.x * 256 + threadIdx.x) * 16;
  #pragma unroll
  for (int c = 0; c < 4; ++c){
    const int e = base + c * 4;
    const int row = e >> 8, col = e & 255;
    const float* src;
    if (row < 256)       src = Wv    + (size_t)row * DK;
    else if (row < 384)  src = Woff  + (size_t)(row - 256) * DK;
    else if (row < 448)  src = Wattn + (size_t)(row - 384) * DK;
    else                 src = Wout  + (size_t)(row - 448) * DK;
    const f4_t v = *(const f4_t*)(src + col);
    s16x4 o = { f2bf(v[0]), f2bf(v[1]), f2bf(v[2]), f2bf(v[3]) };
    *(s16x4*)(Wbf + e) = o;
  }
}

// =============== K1: fused projection GEMM ======================================
// bid < 512:  value-proj tile (BM=64) -> fp8 gather layout vfp8 (LDS-transposed)
// bid >= 512: offset/logit tile (BM=32) -> offw/logit f32
__global__ __launch_bounds__(256, 2) void k_proj(const float* __restrict__ value,
    const float* __restrict__ query, const short* __restrict__ Wbf,
    const float* __restrict__ bval, const float* __restrict__ boff,
    const float* __restrict__ battn, char* __restrict__ vfp8,
    float* __restrict__ offw, float* __restrict__ logit){
  __shared__ short As[64 * 256];
  __shared__ short Bs[64 * 256];
  __shared__ u32 Cs[64 * 16];                 // 4KB fp8 transpose buffer (val path)
  const int tid = threadIdx.x;
  const int lane = tid & 63, wv = tid >> 6;
  const int r16 = lane & 15, kh = lane >> 4;
  const int swsel = (r16 & 7) << 4;
  const int bid = blockIdx.x;

  if (bid < 512){
    // ---------------- value-projection path (BM=64) ----------------
    const float* A = value;
    const short* Bw = Wbf;                     // W_val rows 0..255
    const int mbase = bid * 64;
    #pragma unroll
    for (int i = 0; i < 16; ++i){
      const int lin = i * 256 + tid;
      const int r = lin >> 6, ck = lin & 63;
      const f4_t v = *(const f4_t*)(A + (size_t)(mbase + r) * DK + ck * 4);
      s16x4 o = { f2bf(v[0]), f2bf(v[1]), f2bf(v[2]), f2bf(v[3]) };
      *(s16x4*)((char*)As + r * 512 + ((ck * 8) ^ ((r & 7) << 4))) = o;
    }
    s16x8 breg[8];
    #pragma unroll
    for (int i = 0; i < 8; ++i){
      const int lin = i * 256 + tid;
      const int n = lin >> 5, ck = lin & 31;
      breg[i] = *(const s16x8*)(Bw + (size_t)n * DK + ck * 8);
    }
    __syncthreads();
    for (int cg = 0; cg < 4; ++cg){
      #pragma unroll
      for (int i = 0; i < 8; ++i){
        const int lin = i * 256 + tid;
        const int n = lin >> 5, ck = lin & 31;
        *(s16x8*)((char*)Bs + n * 512 + ((ck * 16) ^ ((n & 7) << 4))) = breg[i];
      }
      __syncthreads();
      if (cg < 3){
        #pragma unroll
        for (int i = 0; i < 8; ++i){
          const int lin = i * 256 + tid;
          const int n = lin >> 5, ck = lin & 31;
          breg[i] = *(const s16x8*)(Bw + (size_t)((cg + 1) * 64 + n) * DK + ck * 8);
        }
      }
      f4_t acc[4];
      #pragma unroll
      for (int i = 0; i < 4; ++i) acc[i] = (f4_t){0.f, 0.f, 0.f, 0.f};
      #pragma unroll
      for (int kk = 0; kk < 8; ++kk){
        const int kb = kh * 16 + kk * 64;
        const s16x8 a = *(const s16x8*)((char*)As + (wv * 16 + r16) * 512 + (kb ^ swsel));
        #pragma unroll
        for (int nt = 0; nt < 4; ++nt){
          const s16x8 b = *(const s16x8*)((char*)Bs + (nt * 16 + r16) * 512 + (kb ^ swsel));
          acc[nt] = __builtin_amdgcn_mfma_f32_16x16x32_bf16(a, b, acc[nt], 0, 0, 0);
        }
      }
      // epilogue: f32 -> fp8, LDS transpose, coalesced 16B stores
      #pragma unroll
      for (int nt = 0; nt < 4; ++nt){
        const int n = cg * 64 + nt * 16 + r16;
        const float bv = bval[n];
        #pragma unroll
        for (int rix = 0; rix < 4; ++rix){
          const float vv = acc[nt][rix] + bv;
          ((char*)Cs)[(wv * 16 + kh * 4 + rix) * 64 + nt * 16 + r16] =
              (char)(pk_fp8(vv, 0.f) & 0xFFu);
        }
      }
      __syncthreads();                          // Cs ready; also fences Bs reads
      {
        const u32x4 cw = *((const u32x4*)((const char*)Cs + tid * 16));
        const int pixl = tid >> 2, q4 = tid & 3;
        const int h2 = cg * 2 + (q4 >> 1);
        const int m = mbase + pixl;
        const int r = m >> 14, pix = m & (QN - 1);
        *(u32x4*)(vfp8 + ((size_t)((r * 8 + h2) * QN + pix)) * 32 + (q4 & 1) * 16) = cw;
      }
    }
  } else {
    // ---------------- offset/logit path (BM=32) ----------------
    const float* A = query;
    const short* Bw = Wbf + 256 * DK;
    const int mg = wv & 1, ch = wv >> 1;
    const int mbase = (bid - 512) * 32;
    #pragma unroll
    for (int i = 0; i < 8; ++i){
      const int lin = i * 256 + tid;
      const int r = lin >> 6, ck = lin & 63;
      const f4_t v = *(const f4_t*)(A + (size_t)(mbase + r) * DK + ck * 4);
      s16x4 o = { f2bf(v[0]), f2bf(v[1]), f2bf(v[2]), f2bf(v[3]) };
      *(s16x4*)((char*)As + r * 512 + ((ck * 8) ^ ((r & 7) << 4))) = o;
    }
    s16x8 breg[8];
    #pragma unroll
    for (int i = 0; i < 8; ++i){
      const int lin = i * 256 + tid;
      const int n = lin >> 5, ck = lin & 31;
      breg[i] = *(const s16x8*)(Bw + (size_t)n * DK + ck * 8);
    }
    __syncthreads();
    for (int cg = 0; cg < 3; ++cg){
      #pragma unroll
      for (int i = 0; i < 8; ++i){
        const int lin = i * 256 + tid;
        const int n = lin >> 5, ck = lin & 31;
        *(s16x8*)((char*)Bs + n * 512 + ((ck * 16) ^ ((n & 7) << 4))) = breg[i];
      }
      __syncthreads();
      if (cg < 2){
        #pragma unroll
        for (int i = 0; i < 8; ++i){
          const int lin = i * 256 + tid;
          const int n = lin >> 5, ck = lin & 31;
          breg[i] = *(const s16x8*)(Bw + (size_t)((cg + 1) * 64 + n) * DK + ck * 8);
        }
      }
      f4_t acc[2];
      acc[0] = (f4_t){0.f,0.f,0.f,0.f}; acc[1] = (f4_t){0.f,0.f,0.f,0.f};
      #pragma unroll
      for (int kk = 0; kk < 8; ++kk){
        const int kb = kh * 16 + kk * 64;
        const s16x8 a = *(const s16x8*)((char*)As + (mg * 16 + r16) * 512 + (kb ^ swsel));
        #pragma unroll
        for (int nt = 0; nt < 2; ++nt){
          const s16x8 b = *(const s16x8*)((char*)Bs + (ch * 32 + nt * 16 + r16) * 512 + (kb ^ swsel));
          acc[nt] = __builtin_amdgcn_mfma_f32_16x16x32_bf16(a, b, acc[nt], 0, 0, 0);
        }
      }
      #pragma unroll
      for (int nt = 0; nt < 2; ++nt){
        const int n = cg * 64 + ch * 32 + nt * 16 + r16;
        #pragma unroll
        for (int rix = 0; rix < 4; ++rix){
          const int m = mbase + mg * 16 + kh * 4 + rix;
          const float v = acc[nt][rix];
          if (n < 128) offw[(size_t)m * 128 + n] = v + boff[n];
          else         logit[(size_t)m * 64 + (n - 128)] = v + battn[n - 128];
        }
      }
      __syncthreads();
    }
  }
}

// =============== K4: output projection + bias + residual, BM=32 =================
__global__ __launch_bounds__(256, 2) void k_gemm_out(const short* __restrict__ Ab,
    const short* __restrict__ Bw, const float* __restrict__ bout,
    const float* __restrict__ query, float* __restrict__ out){
  __shared__ short As[32 * 256];
  __shared__ short Bs[64 * 256];
  const int tid = threadIdx.x;
  const int lane = tid & 63, wv = tid >> 6;
  const int r16 = lane & 15, kh = lane >> 4;
  const int mg = wv & 1, ch = wv >> 1;
  const int swsel = (r16 & 7) << 4;
  const int mbase = blockIdx.x * 32;

  #pragma unroll
  for (int i = 0; i < 4; ++i){
    const int lin = i * 256 + tid;
    const int r = lin >> 5, ck = lin & 31;
    const s16x8 v = *(const s16x8*)(Ab + (size_t)(mbase + r) * DK + ck * 8);
    *(s16x8*)((char*)As + r * 512 + ((ck * 16) ^ ((r & 7) << 4))) = v;
  }
  s16x8 breg[8];
  #pragma unroll
  for (int i = 0; i < 8; ++i){
    const int lin = i * 256 + tid;
    const int n = lin >> 5, ck = lin & 31;
    breg[i] = *(const s16x8*)(Bw + (size_t)n * DK + ck * 8);
  }
  __syncthreads();

  for (int cg = 0; cg < 4; ++cg){
    #pragma unroll
    for (int i = 0; i < 8; ++i){
      const int lin = i * 256 + tid;
      const int n = lin >> 5, ck = lin & 31;
      *(s16x8*)((char*)Bs + n * 512 + ((ck * 16) ^ ((n & 7) << 4))) = breg[i];
    }
    __syncthreads();
    if (cg < 3){
      #pragma unroll
      for (int i = 0; i < 8; ++i){
        const int lin = i * 256 + tid;
        const int n = lin >> 5, ck = lin & 31;
        breg[i] = *(const s16x8*)(Bw + (size_t)((cg + 1) * 64 + n) * DK + ck * 8);
      }
    }
    f4_t acc[2];
    acc[0] = (f4_t){0.f,0.f,0.f,0.f}; acc[1] = (f4_t){0.f,0.f,0.f,0.f};
    #pragma unroll
    for (int kk = 0; kk < 8; ++kk){
      const int kb = kh * 16 + kk * 64;
      const s16x8 a = *(const s16x8*)((char*)As + (mg * 16 + r16) * 512 + (kb ^ swsel));
      #pragma unroll
      for (int nt = 0; nt < 2; ++nt){
        const s16x8 b = *(const s16x8*)((char*)Bs + (ch * 32 + nt * 16 + r16) * 512 + (kb ^ swsel));
        acc[nt] = __builtin_amdgcn_mfma_f32_16x16x32_bf16(a, b, acc[nt], 0, 0, 0);
      }
    }
    #pragma unroll
    for (int nt = 0; nt < 2; ++nt){
      const int n = cg * 64 + ch * 32 + nt * 16 + r16;
      const float bo = bout[n];
      #pragma unroll
      for (int rix = 0; rix < 4; ++rix){
        const int m = mbase + mg * 16 + kh * 4 + rix;
        out[(size_t)m * DK + n] = acc[nt][rix] + bo + query[(size_t)m * DK + n];
      }
    }
    __syncthreads();
  }
}

// ---------------- K3: bilinear sampling, fp8 v-cache, 8-lane groups -------------
// Pixel = 32 B fp8; a row-pair (both x corners) = 64 B = ONE L2 sector.
__device__ inline void mkw(float rx, float ry, float ox, float oy, float awp,
                           u32& word, u32& pk01, u32& pk23){
  const float x = fmaf(rx, 128.f, ox) - 0.5f;
  const float y = fmaf(ry, 128.f, oy) - 0.5f;
  const float xf = floorf(x), yf = floorf(y);
  const float wx = x - xf, wy = y - yf;
  const int ix = (int)xf, iy = (int)yf;
  float xw0 = 1.f - wx, xw1 = wx, yw0 = 1.f - wy, yw1 = wy;
  if (ix < 0 || ix > 127)   xw0 = 0.f;
  if (ix < -1 || ix > 126)  xw1 = 0.f;
  if (iy < 0 || iy > 127)   yw0 = 0.f;
  if (iy < -1 || iy > 126)  yw1 = 0.f;
  const int ix0 = min(max(ix, 0), 127), ix1 = min(max(ix + 1, 0), 127);
  const int iy0 = min(max(iy, 0), 127), iy1 = min(max(iy + 1, 0), 127);
  const float t0 = awp * yw0, t1 = awp * yw1;
  pk01 = pk2h(t0 * xw0, t0 * xw1);     // (row0: x0-w, x1-w) fp16
  pk23 = pk2h(t1 * xw0, t1 * xw1);     // (row1: x0-w, x1-w) fp16
  word = (u32)(iy0 * 128 + ix0) | ((u32)(ix1 - ix0) << 16) | ((u32)(iy1 - iy0) << 17);
}

__global__ __launch_bounds__(256) void k_sampler(const float* __restrict__ rp,
    const float* __restrict__ offw, const float* __restrict__ logit,
    const char* __restrict__ vfp8, short* __restrict__ O2b){
  const int tid = threadIdx.x;
  const int j3 = tid & 7;               // lane in group
  const int cj = j3 & 3;                // hd chunk (8 channels = 8 B fp8)
  const int px = j3 >> 2;               // pixel side (x0 / x1)
  const int grp = tid >> 3;             // query in block: 0..31
  const int lane = tid & 63;
  const int glane8 = lane & ~7;
  const int h = blockIdx.x & 7;
  const int q = (blockIdx.x >> 3) * 32 + grp;
  const u32 cjof = (u32)cj * 8;         // byte offset of my channel chunk
  const u32 selw = px ? 0x03020706u : 0x01000504u;

  // per-lane softmax weight for p = j3 (8-lane shfl_xor reduce)
  const float* lp = logit + (size_t)q * 64 + h * 8;
  const float l = lp[j3];
  float m = l;
  m = fmaxf(m, __shfl_xor(m, 1)); m = fmaxf(m, __shfl_xor(m, 2)); m = fmaxf(m, __shfl_xor(m, 4));
  const float e = __expf(l - m);
  float ssum = e;
  ssum += __shfl_xor(ssum, 1); ssum += __shfl_xor(ssum, 2); ssum += __shfl_xor(ssum, 4);
  const float awp = e * (0.5f / ssum);

  const float* offp = offw + (size_t)q * 128 + h * 16;
  const float ox = offp[2 * j3], oy = offp[2 * j3 + 1];
  const int za2 = (j3 & 3) * 2;
  const float rx0 = rp[(size_t)q * 8 + za2],        ry0 = rp[(size_t)q * 8 + za2 + 1];
  const float rx1 = rp[(size_t)(QN + q) * 8 + za2], ry1 = rp[(size_t)(QN + q) * 8 + za2 + 1];

  u32 wrdA, pkA01, pkA23, wrdB, pkB01, pkB23;
  mkw(rx0, ry0, ox, oy, awp, wrdA, pkA01, pkA23);   // r=0 sample
  mkw(rx1, ry1, ox, oy, awp, wrdB, pkB01, pkB23);   // r=1 sample

  const char* vb0 = vfp8 + (size_t)(h * QN) * 32;
  const char* vb1 = vfp8 + (size_t)((8 + h) * QN) * 32;

  float acc[8] = {0.f,0.f,0.f,0.f,0.f,0.f,0.f,0.f};

#define LOADP(S, WRD, VB)                                                   \
  const u32 wd_##S = __shfl((WRD), glane8 | ((S) & 7));                     \
  const u32 o0_##S = (wd_##S & 0xFFFFu) * 32u + cjof                        \
                   + (px ? ((wd_##S >> 11) & 32u) : 0u);                    \
  const u32 o1_##S = o0_##S + ((wd_##S >> 17) & 1u) * 4096u;                \
  const u32x2 cA_##S = *(const u32x2*)((VB) + o0_##S);  /* row y0, 8 ch */  \
  const u32x2 cB_##S = *(const u32x2*)((VB) + o1_##S);  /* row y1, 8 ch */

#define USEP(S, PK01, PK23) do{                                             \
    const int srcl_ = glane8 | ((S) & 7);                                   \
    const u32 w01_ = __shfl((PK01), srcl_);                                 \
    const u32 w23_ = __shfl((PK23), srcl_);                                 \
    const h2_t wp_ = __builtin_bit_cast(h2_t, bperm(w01_, w23_, selw));     \
    const float w0_ = (float)wp_[0], w1_ = (float)wp_[1];                   \
    _Pragma("unroll")                                                       \
    for (int wdi_ = 0; wdi_ < 2; ++wdi_){                                   \
      const f2_t aL_ = upk_fp8<false>(cA_##S[wdi_]);                        \
      const f2_t aH_ = upk_fp8<true >(cA_##S[wdi_]);                        \
      const f2_t bL_ = upk_fp8<false>(cB_##S[wdi_]);                        \
      const f2_t bH_ = upk_fp8<true >(cB_##S[wdi_]);                        \
      acc[4*wdi_+0] = fmaf(w0_, aL_[0], fmaf(w1_, bL_[0], acc[4*wdi_+0]));  \
      acc[4*wdi_+1] = fmaf(w0_, aL_[1], fmaf(w1_, bL_[1], acc[4*wdi_+1]));  \
      acc[4*wdi_+2] = fmaf(w0_, aH_[0], fmaf(w1_, bH_[0], acc[4*wdi_+2]));  \
      acc[4*wdi_+3] = fmaf(w0_, aH_[1], fmaf(w1_, bH_[1], acc[4*wdi_+3]));  \
    }                                                                       \
  }while(0)

  LOADP(0,  wrdA, vb0) LOADP(1,  wrdA, vb0) LOADP(2,  wrdA, vb0)
  USEP(0,  pkA01, pkA23); LOADP(3,  wrdA, vb0)
  USEP(1,  pkA01, pkA23); LOADP(4,  wrdA, vb0)
  USEP(2,  pkA01, pkA23); LOADP(5,  wrdA, vb0)
  USEP(3,  pkA01, pkA23); LOADP(6,  wrdA, vb0)
  USEP(4,  pkA01, pkA23); LOADP(7,  wrdA, vb0)
  USEP(5,  pkA01, pkA23); LOADP(8,  wrdB, vb1)
  USEP(6,  pkA01, pkA23); LOADP(9,  wrdB, vb1)
  USEP(7,  pkA01, pkA23); LOADP(10, wrdB, vb1)
  USEP(8,  pkB01, pkB23); LOADP(11, wrdB, vb1)
  USEP(9,  pkB01, pkB23); LOADP(12, wrdB, vb1)
  USEP(10, pkB01, pkB23); LOADP(13, wrdB, vb1)
  USEP(11, pkB01, pkB23); LOADP(14, wrdB, vb1)
  USEP(12, pkB01, pkB23); LOADP(15, wrdB, vb1)
  USEP(13, pkB01, pkB23);
  USEP(14, pkB01, pkB23);
  USEP(15, pkB01, pkB23);
#undef LOADP
#undef USEP

  // combine pixel-side partials (px=0 + px=1), write bf16 O2
  #pragma unroll
  for (int i = 0; i < 8; ++i) acc[i] += __shfl_xor(acc[i], 4);
  if (px == 0){
    s16x8 o = { f2bf(acc[0]), f2bf(acc[1]), f2bf(acc[2]), f2bf(acc[3]),
                f2bf(acc[4]), f2bf(acc[5]), f2bf(acc[6]), f2bf(acc[7]) };
    *(s16x8*)(O2b + (size_t)q * DK + h * 32 + cj * 8) = o;
  }
}

extern "C" void kernel_launch(void* const* d_in, const int* in_sizes, int n_in,
                              void* d_out, int out_size, void* d_ws, size_t ws_size,
                              hipStream_t stream) {
  const float* query = (const float*)d_in[0];
  const float* value = (const float*)d_in[1];
  const float* refpt = (const float*)d_in[2];
  // d_in[3] spatial_shapes: fixed [[128,128]], hardcoded
  const float* W_off  = (const float*)d_in[4];
  const float* b_off  = (const float*)d_in[5];
  const float* W_attn = (const float*)d_in[6];
  const float* b_attn = (const float*)d_in[7];
  const float* W_val  = (const float*)d_in[8];
  const float* b_val  = (const float*)d_in[9];
  const float* W_out  = (const float*)d_in[10];
  const float* b_out  = (const float*)d_in[11];
  float* out = (float*)d_out;

  char* ws = (char*)d_ws;
  short* Wbf  = (short*)(ws);                    // 704*256 bf16          (360448 B)
  char*  vfp8 = (char*)(ws + 360448);            // 2*8*16384*32 fp8      (8388608 B)
  float* offw = (float*)(ws + 8749056);          // 16384*128 f32         (8388608 B)
  float* logit= (float*)(ws + 17137664);         // 16384*64 f32          (4194304 B)
  short* O2b  = (short*)(ws + 21331968);         // 16384*256 bf16        (8388608 B)

  k_convw   <<<dim3(44),   dim3(256), 0, stream>>>(W_val, W_off, W_attn, W_out, Wbf);
  k_proj    <<<dim3(1024), dim3(256), 0, stream>>>(value, query, Wbf, b_val, b_off,
                                                   b_attn, vfp8, offw, logit);
  k_sampler <<<dim3(4096), dim3(256), 0, stream>>>(refpt, offw, logit, vfp8, O2b);
  k_gemm_out<<<dim3(512),  dim3(256), 0, stream>>>(O2b, Wbf + 448 * DK, b_out, query, out);
}